// Round 19
// baseline (205.122 us; speedup 1.0000x reference)
//
#include <hip/hip_runtime.h>
#include <cstdint>
#include <cstddef>

#define D_MODEL   1024
#define D_STATE   64
#define D_CONV    4
#define HEADDIM   128
#define NHEADS    16
#define D_INNER   2048
#define CONV_DIM  2176          // D_INNER + 2*D_STATE
#define D_IN_PROJ 4240          // 2*D_INNER + 2*D_STATE + NHEADS
#define NPAD      4352          // D_IN_PROJ padded to multiple of 128
#define BATCH     2
#define SEQLEN    2048
#define NROWS     (BATCH*SEQLEN)   // 4096
#define CHUNK     64
#define NCHUNK    (SEQLEN/CHUNK)   // 32

using u16   = unsigned short;
using s16x8 = __attribute__((ext_vector_type(8))) short;   // 8 bf16 (4 VGPRs)
using f32x4 = __attribute__((ext_vector_type(4))) float;   // MFMA accumulator

// ---------------------------------------------------------------------------
// helpers
// ---------------------------------------------------------------------------
__device__ __forceinline__ u16 f2bf(float f) {
    union { float f; unsigned u; } v; v.f = f;
    unsigned r = v.u + 0x7fffu + ((v.u >> 16) & 1u);   // round-to-nearest-even
    return (u16)(r >> 16);
}
__device__ __forceinline__ float bf2f(u16 x) {
    union { unsigned u; float f; } v; v.u = ((unsigned)x) << 16;
    return v.f;
}

__device__ __forceinline__ void gload16(const u16* g, u16* l) {
    __builtin_amdgcn_global_load_lds(
        (const __attribute__((address_space(1))) unsigned int*)g,
        (__attribute__((address_space(3))) unsigned int*)l, 16, 0, 0);
}

__device__ __forceinline__ void cp8(const float* in, u16* out, int i) {
    const float4* p = (const float4*)(in + (size_t)i * 8);
    float4 a = p[0], b = p[1];
    u16 o[8] = {f2bf(a.x), f2bf(a.y), f2bf(a.z), f2bf(a.w),
                f2bf(b.x), f2bf(b.y), f2bf(b.z), f2bf(b.w)};
    *(uint4*)(out + (size_t)i * 8) = *(const uint4*)o;
}

// ---------------------------------------------------------------------------
// merged f32 -> bf16 conversion: u | in_proj_w (row-padded) | out_proj_w
// ---------------------------------------------------------------------------
#define CVT_N0 (NROWS*D_MODEL/8)      // 524288
#define CVT_N1 (NPAD*128)             // 557056
#define CVT_N2 (D_MODEL*D_INNER/8)    // 262144
__global__ __launch_bounds__(256) void cvt_all(
    const float* __restrict__ u, const float* __restrict__ w_in,
    const float* __restrict__ w_out,
    u16* __restrict__ u_bf, u16* __restrict__ w_in_bf, u16* __restrict__ w_out_bf)
{
    int i = blockIdx.x * 256 + threadIdx.x;
    if (i < CVT_N0) {
        cp8(u, u_bf, i);
    } else if (i < CVT_N0 + CVT_N1) {
        int j = i - CVT_N0;
        int row = j >> 7, seg = j & 127;
        u16 o[8] = {0,0,0,0,0,0,0,0};
        if (row < D_IN_PROJ) {
            const float4* p = (const float4*)(w_in + (size_t)row * D_MODEL + seg * 8);
            float4 a = p[0], b = p[1];
            o[0]=f2bf(a.x); o[1]=f2bf(a.y); o[2]=f2bf(a.z); o[3]=f2bf(a.w);
            o[4]=f2bf(b.x); o[5]=f2bf(b.y); o[6]=f2bf(b.z); o[7]=f2bf(b.w);
        }
        *(uint4*)(w_in_bf + (size_t)j * 8) = *(const uint4*)o;
    } else if (i < CVT_N0 + CVT_N1 + CVT_N2) {
        cp8(w_out, w_out_bf, i - CVT_N0 - CVT_N1);
    }
}

// ---------------------------------------------------------------------------
// in_proj GEMM: 128x128 tile, BK=64, 8 waves (512 thr), counted vmcnt(4),
// T2 swizzle, rect per-XCD mapping, LDS-staged coalesced epilogue.
// ---------------------------------------------------------------------------
#define CPITCH 136    // u16 pitch for epilogue tile (272B rows, 16B aligned)
__global__ __launch_bounds__(512) void gemm_in512(
    const u16* __restrict__ A, const u16* __restrict__ B, int K,
    u16* __restrict__ C0, int n1, int ld0,
    u16* __restrict__ C1, int n2, int ld1,
    u16* __restrict__ C2, int n3, int ld2)
{
    __shared__ u16 smem[4 * 128 * 64];          // 64 KB arena

    const int tid  = threadIdx.x;
    const int wid  = tid >> 6;               // 0..7
    const int lane = tid & 63;
    const int wm   = wid >> 2, wn = wid & 3; // 2 x 4 wave grid

    // rectangular XCD mapping: grid 34x32 = 1088 = 8 XCD x (8m x 17n)
    const int gx   = gridDim.x;                  // 34
    int orig = blockIdx.y * gx + blockIdx.x;     // 0..1087
    const int xcd = orig & 7;
    const int loc = orig >> 3;                   // 0..135
    const int mt  = (xcd >> 1) * 8  + (loc & 7); // 0..31
    const int nt  = (xcd & 1) * 17 + (loc >> 3); // 0..33
    const int m0 = mt * 128, n0 = nt * 128;

    const int lrow = lane >> 3;
    const int lseg = (lane & 7) ^ lrow;
    const u16* gA = A + (size_t)(m0 + lrow) * K + lseg * 8;
    const u16* gB = B + (size_t)(n0 + lrow) * K + lseg * 8;

    f32x4 acc[4][2];
    #pragma unroll
    for (int i = 0; i < 4; ++i)
        #pragma unroll
        for (int j = 0; j < 2; ++j)
            acc[i][j] = (f32x4){0.f, 0.f, 0.f, 0.f};

    const int fr = lane & 15, fq = lane >> 4;
    const int nstep = K >> 6;

    auto stage = [&](int buf, int k0) {
        u16* sAp = smem + buf * 8192;
        u16* sBp = smem + 16384 + buf * 8192;
        #pragma unroll
        for (int i = 0; i < 2; ++i) {
            const int r0 = (i * 8 + wid) * 8;
            gload16(gA + (size_t)r0 * K + k0, sAp + r0 * 64);
            gload16(gB + (size_t)r0 * K + k0, sBp + r0 * 64);
        }
    };

    stage(0, 0);
    int cur = 0;
    for (int step = 0; step < nstep; ++step) {
        if (step + 1 < nstep) {
            stage(cur ^ 1, (step + 1) * 64);
            asm volatile("s_waitcnt vmcnt(4)" ::: "memory");
        } else {
            asm volatile("s_waitcnt vmcnt(0)" ::: "memory");
        }
        __builtin_amdgcn_s_barrier();
        __builtin_amdgcn_sched_barrier(0);

        const u16* sAc = smem + cur * 8192;
        const u16* sBc = smem + 16384 + cur * 8192;
        #pragma unroll
        for (int ks = 0; ks < 2; ++ks) {
            s16x8 bfr[2];
            #pragma unroll
            for (int ni = 0; ni < 2; ++ni) {
                const int row = wn * 32 + ni * 16 + fr;
                const int bo = row * 128 + ((ks * 64 + fq * 16) ^ ((row & 7) << 4));
                bfr[ni] = *(const s16x8*)((const char*)sBc + bo);
            }
            #pragma unroll
            for (int mi = 0; mi < 4; ++mi) {
                const int row = wm * 64 + mi * 16 + fr;
                const int bo = row * 128 + ((ks * 64 + fq * 16) ^ ((row & 7) << 4));
                s16x8 af = *(const s16x8*)((const char*)sAc + bo);
                #pragma unroll
                for (int ni = 0; ni < 2; ++ni)
                    acc[mi][ni] = __builtin_amdgcn_mfma_f32_16x16x32_bf16(
                        af, bfr[ni], acc[mi][ni], 0, 0, 0);
            }
        }

        __builtin_amdgcn_sched_barrier(0);
        __builtin_amdgcn_s_barrier();
        cur ^= 1;
    }
    __builtin_amdgcn_sched_barrier(0);   // keep epilogue ds_writes after loop

    // ---- LDS-staged epilogue: frag layout -> row-linear -> 16B stores ----
    u16* sC = smem;                       // K-loop buffers dead now
    #pragma unroll
    for (int mi = 0; mi < 4; ++mi) {
        #pragma unroll
        for (int j = 0; j < 4; ++j) {
            const int rl = wm * 64 + mi * 16 + fq * 4 + j;
            #pragma unroll
            for (int ni = 0; ni < 2; ++ni) {
                const int cl = wn * 32 + ni * 16 + fr;
                sC[rl * CPITCH + cl] = f2bf(acc[mi][ni][j]);
            }
        }
    }
    __syncthreads();
    #pragma unroll
    for (int k2 = 0; k2 < 4; ++k2) {
        const int g  = tid + k2 * 512;        // 0..2047
        const int rl = g >> 4, cg = g & 15;
        uint4 v = *(const uint4*)&sC[rl * CPITCH + cg * 8];
        const int r = m0 + rl, c = n0 + cg * 8;
        if (c < n1)      *(uint4*)(C0 + (size_t)r * ld0 + c)        = v;
        else if (c < n2) *(uint4*)(C1 + (size_t)r * ld1 + (c - n1)) = v;
        else if (c < n3) *(uint4*)(C2 + (size_t)r * ld2 + (c - n2)) = v;
    }
}

// ---------------------------------------------------------------------------
// out_proj GEMM: 128x128 tile, BK=64, 8 waves (512 thr), counted vmcnt(4),
// LDS-staged f32 epilogue in two 64-row halves (coalesced 16B stores).
// ---------------------------------------------------------------------------
__global__ __launch_bounds__(512) void gemm_out512(
    const u16* __restrict__ A, const u16* __restrict__ B, int K,
    float* __restrict__ C, int N)
{
    __shared__ u16 smem[4 * 128 * 64];          // 64 KB arena

    const int tid  = threadIdx.x;
    const int wid  = tid >> 6;               // 0..7
    const int lane = tid & 63;
    const int wm   = wid >> 2, wn = wid & 3; // 2 x 4 wave grid

    const int gx   = gridDim.x;
    const int nwg  = gx * gridDim.y;
    const int cpx  = nwg >> 3;
    int orig = blockIdx.y * gx + blockIdx.x;
    int wg   = (orig & 7) * cpx + (orig >> 3);
    const int m0 = (wg / gx) * 128, n0 = (wg % gx) * 128;

    const int lrow = lane >> 3;
    const int lseg = (lane & 7) ^ lrow;
    const u16* gA = A + (size_t)(m0 + lrow) * K + lseg * 8;
    const u16* gB = B + (size_t)(n0 + lrow) * K + lseg * 8;

    f32x4 acc[4][2];
    #pragma unroll
    for (int i = 0; i < 4; ++i)
        #pragma unroll
        for (int j = 0; j < 2; ++j)
            acc[i][j] = (f32x4){0.f, 0.f, 0.f, 0.f};

    const int fr = lane & 15, fq = lane >> 4;
    const int nstep = K >> 6;

    auto stage = [&](int buf, int k0) {
        u16* sAp = smem + buf * 8192;
        u16* sBp = smem + 16384 + buf * 8192;
        #pragma unroll
        for (int i = 0; i < 2; ++i) {
            const int r0 = (i * 8 + wid) * 8;
            gload16(gA + (size_t)r0 * K + k0, sAp + r0 * 64);
            gload16(gB + (size_t)r0 * K + k0, sBp + r0 * 64);
        }
    };

    stage(0, 0);
    int cur = 0;
    for (int step = 0; step < nstep; ++step) {
        if (step + 1 < nstep) {
            stage(cur ^ 1, (step + 1) * 64);
            asm volatile("s_waitcnt vmcnt(4)" ::: "memory");
        } else {
            asm volatile("s_waitcnt vmcnt(0)" ::: "memory");
        }
        __builtin_amdgcn_s_barrier();
        __builtin_amdgcn_sched_barrier(0);

        const u16* sAc = smem + cur * 8192;
        const u16* sBc = smem + 16384 + cur * 8192;
        #pragma unroll
        for (int ks = 0; ks < 2; ++ks) {
            s16x8 bfr[2];
            #pragma unroll
            for (int ni = 0; ni < 2; ++ni) {
                const int row = wn * 32 + ni * 16 + fr;
                const int bo = row * 128 + ((ks * 64 + fq * 16) ^ ((row & 7) << 4));
                bfr[ni] = *(const s16x8*)((const char*)sBc + bo);
            }
            #pragma unroll
            for (int mi = 0; mi < 4; ++mi) {
                const int row = wm * 64 + mi * 16 + fr;
                const int bo = row * 128 + ((ks * 64 + fq * 16) ^ ((row & 7) << 4));
                s16x8 af = *(const s16x8*)((const char*)sAc + bo);
                #pragma unroll
                for (int ni = 0; ni < 2; ++ni)
                    acc[mi][ni] = __builtin_amdgcn_mfma_f32_16x16x32_bf16(
                        af, bfr[ni], acc[mi][ni], 0, 0, 0);
            }
        }

        __builtin_amdgcn_sched_barrier(0);
        __builtin_amdgcn_s_barrier();
        cur ^= 1;
    }
    __builtin_amdgcn_sched_barrier(0);

    // ---- LDS-staged f32 epilogue, two 64-row halves (pitch 132 f32) ----
    float* sCf = (float*)smem;            // 64x132x4 = 33.8 KB per half
    #pragma unroll
    for (int h2 = 0; h2 < 2; ++h2) {
        if (wm == h2) {
            #pragma unroll
            for (int mi = 0; mi < 4; ++mi)
                #pragma unroll
                for (int j = 0; j < 4; ++j) {
                    const int rl = mi * 16 + fq * 4 + j;        // 0..63
                    #pragma unroll
                    for (int ni = 0; ni < 2; ++ni) {
                        const int cl = wn * 32 + ni * 16 + fr;
                        sCf[rl * 132 + cl] = acc[mi][ni][j];
                    }
                }
        }
        __syncthreads();
        #pragma unroll
        for (int k2 = 0; k2 < 4; ++k2) {
            const int g  = tid + k2 * 512;    // 0..2047
            const int rl = g >> 5, cg = g & 31;
            float4 v = *(const float4*)&sCf[rl * 132 + cg * 4];
            *(float4*)(C + (size_t)(m0 + h2 * 64 + rl) * N + n0 + cg * 4) = v;
        }
        __syncthreads();
    }
}

// ---------------------------------------------------------------------------
// Depthwise causal conv(4)+bias+SiLU (8 ch/thread) and, in tail blocks,
// dt = softplus(dtraw + dt_bias)  (merged to save a dispatch).
// ---------------------------------------------------------------------------
#define NCONV8 (NROWS*(CONV_DIM/8))
__global__ __launch_bounds__(256) void conv_silu_dt(
    const u16* __restrict__ xBC, const float* __restrict__ conv_w,
    const float* __restrict__ conv_b, u16* __restrict__ xconv,
    const u16* __restrict__ dtraw, const float* __restrict__ dt_bias,
    float* __restrict__ dtw)
{
    int idx = blockIdx.x * 256 + threadIdx.x;
    if (idx < NCONV8) {
        int c8  = idx % (CONV_DIM / 8);
        int row = idx / (CONV_DIM / 8);     // b*SEQLEN + l
        int l   = row % SEQLEN;
        int b   = row / SEQLEN;
        int c0  = c8 * 8;
        const u16* src = xBC + (size_t)(b * SEQLEN) * CONV_DIM + c0;

        uint4 z4 = {0u, 0u, 0u, 0u};
        uint4 v3 = *(const uint4*)(src + (size_t)l * CONV_DIM);
        uint4 v2 = (l >= 1) ? *(const uint4*)(src + (size_t)(l-1) * CONV_DIM) : z4;
        uint4 v1 = (l >= 2) ? *(const uint4*)(src + (size_t)(l-2) * CONV_DIM) : z4;
        uint4 v0 = (l >= 3) ? *(const uint4*)(src + (size_t)(l-3) * CONV_DIM) : z4;
        const u16* p0 = (const u16*)&v0; const u16* p1 = (const u16*)&v1;
        const u16* p2 = (const u16*)&v2; const u16* p3 = (const u16*)&v3;

        u16 o[8];
        #pragma unroll
        for (int j = 0; j < 8; ++j) {
            const float4 w4 = *(const float4*)(conv_w + (size_t)(c0 + j) * 4);
            float acc = conv_b[c0 + j]
                      + bf2f(p0[j]) * w4.x + bf2f(p1[j]) * w4.y
                      + bf2f(p2[j]) * w4.z + bf2f(p3[j]) * w4.w;
            o[j] = f2bf(acc / (1.f + expf(-acc)));   // SiLU
        }
        *(uint4*)(xconv + (size_t)row * CONV_DIM + c0) = *(const uint4*)o;
    } else {
        int k = idx - NCONV8;
        if (k < NROWS * NHEADS) {
            int h = k & (NHEADS - 1);
            float v = bf2f(dtraw[k]) + dt_bias[h];
            dtw[k] = (v > 20.f) ? v : log1pf(expf(v));
        }
    }
}

// ---------------------------------------------------------------------------
// Phase A: chunk state.  S[n][p] = sum_s (W_s*B_s[n]) * x_s[p]  (bf16 out)
// sWB now bf16 (8 KB): block LDS ~25 KB => 6 blocks/CU.
// ---------------------------------------------------------------------------
__global__ __launch_bounds__(256) void chunk_state(
    const u16* __restrict__ xconv, const float* __restrict__ dtw,
    const float* __restrict__ A_log, u16* __restrict__ Sbuf,
    float* __restrict__ Tbuf)
{
    const int blk = blockIdx.x;
    const int k  = blk & (NCHUNK-1);
    const int bh = blk >> 5;
    const int b  = bh >> 4, h = bh & 15;
    const int tid = threadIdx.x;
    const int wid = tid >> 6, lane = tid & 63;
    const float A = -expf(A_log[h]);

    __shared__ float sdt[CHUNK], sW[CHUNK], sT;
    __shared__ u16   sWB16[CHUNK * D_STATE];   // bf16, 128B rows, swz 16B units
    __shared__ u16   sX[CHUNK * HEADDIM];      // linear (DMA-staged)

    const int t0 = k * CHUNK;
    const u16* xc = xconv + (size_t)(b*SEQLEN + t0) * CONV_DIM;

    if (tid < CHUNK)
        sdt[tid] = dtw[(size_t)(b*SEQLEN + t0 + tid)*NHEADS + h];
    __syncthreads();
    if (tid < CHUNK) {
        float a = 0.f, pref = 0.f;
        for (int r = 0; r < CHUNK; ++r) {
            a += sdt[r] * A;
            if (r == tid) pref = a;
        }
        sW[tid] = __expf(a - pref) * sdt[tid];   // exp(T - L_s) * dt_s
        if (tid == 0) sT = a;
    }
    __syncthreads();

    // stage x via DMA: 4 calls/wave, 4 rows per call
    #pragma unroll
    for (int c = 0; c < 4; ++c) {
        const int r = wid * 16 + c * 4 + (lane >> 4);
        const int seg = lane & 15;
        gload16(xc + (size_t)r * CONV_DIM + h * HEADDIM + seg * 8,
                sX + (wid * 16 + c * 4) * HEADDIM);
    }
    // stage W*B (bf16, 128B rows, 16B-unit XOR swizzle)
    {
        const int s = tid >> 2, nb = tid & 3;
        const float wv = sW[s];
        uint4 b0 = *(const uint4*)(xc + (size_t)s*CONV_DIM + D_INNER + nb*16);
        uint4 b1 = *(const uint4*)(xc + (size_t)s*CONV_DIM + D_INNER + nb*16 + 8);
        const u16* pb0 = (const u16*)&b0; const u16* pb1 = (const u16*)&b1;
        u16 o[16];
        #pragma unroll
        for (int j = 0; j < 8; ++j) {
            o[j]     = f2bf(wv * bf2f(pb0[j]));
            o[8 + j] = f2bf(wv * bf2f(pb1[j]));
        }
        #pragma unroll
        for (int u2 = 0; u2 < 2; ++u2) {
            const int bo = s * 128 + ((nb * 32 + u2 * 16) ^ ((s & 7) << 4));
            *(uint4*)((char*)sWB16 + bo) = *(const uint4*)&o[u2 * 8];
        }
    }
    __syncthreads();

    // compute: thread (nn, pp) -> 4n x 8p
    const int nn = tid >> 4, pp = tid & 15;
    const int p0 = pp * 8, n0 = nn * 4;
    const int base16 = (nn >> 1) << 4;       // 16B granule of this nn's 8B read
    const int sub8   = (nn & 1) * 8;
    float acc[4][8];
    #pragma unroll
    for (int i = 0; i < 4; ++i)
        #pragma unroll
        for (int j = 0; j < 8; ++j) acc[i][j] = 0.f;

    for (int s = 0; s < CHUNK; ++s) {
        const int bo = s * 128 + ((base16 ^ ((s & 7) << 4)) + sub8);
        uint2 wv2 = *(const uint2*)((const char*)sWB16 + bo);
        const u16* wp = (const u16*)&wv2;
        const float w0f = bf2f(wp[0]), w1f = bf2f(wp[1]);
        const float w2f = bf2f(wp[2]), w3f = bf2f(wp[3]);
        uint4 xv = *(const uint4*)&sX[s * HEADDIM + p0];
        const u16* xp = (const u16*)&xv;
        #pragma unroll
        for (int j = 0; j < 8; ++j) {
            const float xf = bf2f(xp[j]);
            acc[0][j] += w0f * xf;
            acc[1][j] += w1f * xf;
            acc[2][j] += w2f * xf;
            acc[3][j] += w3f * xf;
        }
    }
    u16* So = Sbuf + ((size_t)bh*NCHUNK + k)*(D_STATE*HEADDIM);
    #pragma unroll
    for (int i = 0; i < 4; ++i) {
        u16 o[8];
        #pragma unroll
        for (int j = 0; j < 8; ++j) o[j] = f2bf(acc[i][j]);
        *(uint4*)(So + (size_t)(n0 + i) * HEADDIM + p0) = *(const uint4*)o;
    }
    if (tid == 0) Tbuf[bh*NCHUNK + k] = sT;
}

// ---------------------------------------------------------------------------
// Inter-chunk sequential pass (bf16 S, f32 accumulation), parallel over (n,p)
// ---------------------------------------------------------------------------
__global__ __launch_bounds__(256) void chunk_seq_par(u16* __restrict__ Sbuf,
                                                     const float* __restrict__ Tbuf)
{
    const int blk = blockIdx.x;           // 32 bh * 8 = 256 blocks
    const int bh  = blk >> 3;
    const int sub = blk & 7;
    __shared__ float seT[NCHUNK];
    if (threadIdx.x < NCHUNK)
        seT[threadIdx.x] = __expf(Tbuf[bh*NCHUNK + threadIdx.x]);
    __syncthreads();

    const int idx4 = sub * 256 + threadIdx.x;    // 4-elem index in [0,2048)
    u16* base = Sbuf + (size_t)bh*NCHUNK*(D_STATE*HEADDIM) + (size_t)idx4*4;
    float run[4];
    #pragma unroll
    for (int j = 0; j < 4; ++j) run[j] = 0.f;
    for (int k = 0; k < NCHUNK; ++k) {
        u16* p = base + (size_t)k * (D_STATE*HEADDIM);
        uint2 v = *(const uint2*)p;
        const u16* pv = (const u16*)&v;
        const float eT = seT[k];
        u16 o[4];
        #pragma unroll
        for (int j = 0; j < 4; ++j) {
            float tmp = bf2f(pv[j]);
            o[j] = f2bf(run[j]);
            run[j] = run[j] * eT + tmp;
        }
        *(uint2*)p = *(const uint2*)o;
    }
}

// ---------------------------------------------------------------------------
// Phase B: chunk outputs (bf16 sMt, 4 blocks/CU)
// ---------------------------------------------------------------------------
__global__ __launch_bounds__(256) void chunk_output(
    const u16* __restrict__ xconv, const float* __restrict__ dtw,
    const float* __restrict__ A_log, const float* __restrict__ D_param,
    const u16* __restrict__ Sbuf, u16* __restrict__ y)
{
    const int blk = blockIdx.x;
    const int k  = blk & (NCHUNK-1);
    const int bh = blk >> 5;
    const int b  = bh >> 4, h = bh & 15;
    const int tid = threadIdx.x;
    const int wid = tid >> 6, lane = tid & 63;
    const float A  = -expf(A_log[h]);
    const float Dp = D_param[h];

    __shared__ float sdt[CHUNK], sL[CHUNK], seL[CHUNK];
    __shared__ u16   sMt16[(CHUNK + D_STATE) * CHUNK];  // bf16, swz, 128B rows
    __shared__ u16   sX[CHUNK * HEADDIM];               // linear (DMA-staged)

    const int t0 = k * CHUNK;
    const u16* xc = xconv + (size_t)(b*SEQLEN + t0) * CONV_DIM;

    if (tid < CHUNK)
        sdt[tid] = dtw[(size_t)(b*SEQLEN + t0 + tid)*NHEADS + h];
    __syncthreads();
    if (tid < CHUNK) {
        float a = 0.f, pref = 0.f;
        for (int r = 0; r < CHUNK; ++r) {
            a += sdt[r] * A;
            if (r == tid) pref = a;
        }
        sL[tid]  = pref;
        seL[tid] = __expf(pref);
    }
    __syncthreads();

    // ---- stage x via DMA (overlaps with MFMA below) ----
    #pragma unroll
    for (int c = 0; c < 4; ++c) {
        const int r = wid * 16 + c * 4 + (lane >> 4);
        const int seg = lane & 15;
        gload16(xc + (size_t)r * CONV_DIM + h * HEADDIM + seg * 8,
                sX + (wid * 16 + c * 4) * HEADDIM);
    }

    // ---- G = C @ B^T via MFMA; decay epilogue -> sMt16 (bf16) ----
    {
        const int fr = lane & 15, fq = lane >> 4;
        const int t_row = wid * 16 + fr;
        s16x8 cfrag[2];
        #pragma unroll
        for (int ks = 0; ks < 2; ++ks)
            cfrag[ks] = *(const s16x8*)(xc + (size_t)t_row*CONV_DIM + D_INNER + D_STATE
                                        + ks*32 + fq*8);
        float4 sL4 = *(const float4*)&sL[wid * 16 + fq * 4];
        const float Lt[4] = {sL4.x, sL4.y, sL4.z, sL4.w};

        #pragma unroll
        for (int sf = 0; sf < 4; ++sf) {
            const int s_row = sf * 16 + fr;
            f32x4 g = (f32x4){0.f, 0.f, 0.f, 0.f};
            #pragma unroll
            for (int ks = 0; ks < 2; ++ks) {
                s16x8 bfrag = *(const s16x8*)(xc + (size_t)s_row*CONV_DIM + D_INNER
                                              + ks*32 + fq*8);
                g = __builtin_amdgcn_mfma_f32_16x16x32_bf16(cfrag[ks], bfrag, g, 0, 0, 0);
            }
            const float Ls  = sL[s_row];
            const float dts = sdt[s_row];
            u16 o[4];
            #pragma unroll
            for (int r = 0; r < 4; ++r) {
                const int t = wid * 16 + fq * 4 + r;
                const float e = __expf(fminf(Lt[r] - Ls, 0.f)) * dts;
                o[r] = f2bf((s_row <= t) ? g[r] * e : 0.f);
            }
            const int bo2 = s_row * 128 + ((wid * 32 + fq * 8) ^ ((s_row & 7) << 4));
            *(uint2*)((char*)sMt16 + bo2) = *(const uint2*)o;
        }
    }

    // ---- Mext rows: sMt16[64+n][t] = exp(L_t) * C_t[n] ----
    {
        const int t = tid >> 2, nb = tid & 3;
        const float el = seL[t];
        uint4 c0 = *(const uint4*)(xc + (size_t)t*CONV_DIM + D_INNER + D_STATE + nb*16);
        uint4 c1 = *(const uint4*)(xc + (size_t)t*CONV_DIM + D_INNER + D_STATE + nb*16 + 8);
        const u16* pc0 = (const u16*)&c0; const u16* pc1 = (const u16*)&c1;
        #pragma unroll
        for (int j = 0; j < 16; ++j) {
            const int n = nb * 16 + j;
            const float v = el * bf2f(j < 8 ? pc0[j] : pc1[j - 8]);
            const int bo2 = (CHUNK + n) * 128 + ((t * 2) ^ ((n & 7) << 4));
            *(u16*)((char*)sMt16 + bo2) = f2bf(v);
        }
    }
    __syncthreads();

    // ---- Stage B: thread (tt, pp) -> 4t x 8p ----
    const int tt = tid >> 4, pp = tid & 15;
    const int p0 = pp * 8;
    float acc[4][8];
    #pragma unroll
    for (int i = 0; i < 4; ++i)
        #pragma unroll
        for (int j = 0; j < 8; ++j) acc[i][j] = 0.f;

    const int smax = tt * 4 + 4;      // causal: s <= t_max of this thread
    for (int s = 0; s < smax; ++s) {
        const int bo = s * 128 + ((tt * 8) ^ ((s & 7) << 4));
        uint2 mv = *(const uint2*)((const char*)sMt16 + bo);
        const u16* mp = (const u16*)&mv;
        const float m0f = bf2f(mp[0]), m1f = bf2f(mp[1]);
        const float m2f = bf2f(mp[2]), m3f = bf2f(mp[3]);
        uint4 xv = *(const uint4*)&sX[s * HEADDIM + p0];
        const u16* xp = (const u16*)&xv;
        #pragma unroll
        for (int j = 0; j < 8; ++j) {
            const float xf = bf2f(xp[j]);
            acc[0][j] += m0f * xf;
            acc[1][j] += m1f * xf;
            acc[2][j] += m2f * xf;
            acc[3][j] += m3f * xf;
        }
    }
    const u16* Sinit = Sbuf + ((size_t)bh*NCHUNK + k)*(D_STATE*HEADDIM);
    for (int n = 0; n < D_STATE; ++n) {
        const int bo = (CHUNK + n) * 128 + ((tt * 8) ^ ((n & 7) << 4));
        uint2 mv = *(const uint2*)((const char*)sMt16 + bo);
        const u16* mp = (const u16*)&mv;
        const float m0f = bf2f(mp[0]), m1f = bf2f(mp[1]);
        const float m2f = bf2f(mp[2]), m3f = bf2f(mp[3]);
        uint4 sv = *(const uint4*)(Sinit + (size_t)n * HEADDIM + p0);
        const u16* sp = (const u16*)&sv;
        #pragma unroll
        for (int j = 0; j < 8; ++j) {
            const float sf = bf2f(sp[j]);
            acc[0][j] += m0f * sf;
            acc[1][j] += m1f * sf;
            acc[2][j] += m2f * sf;
            acc[3][j] += m3f * sf;
        }
    }
    #pragma unroll
    for (int i = 0; i < 4; ++i) {
        const int t = tt * 4 + i;
        uint4 xv = *(const uint4*)&sX[t * HEADDIM + p0];
        const u16* xp = (const u16*)&xv;
        u16 o[8];
        #pragma unroll
        for (int j = 0; j < 8; ++j)
            o[j] = f2bf(acc[i][j] + Dp * bf2f(xp[j]));
        *(uint4*)(y + ((size_t)(b*SEQLEN + t0 + t))*D_INNER + h*HEADDIM + p0)
            = *(const uint4*)o;
    }
}

// ---------------------------------------------------------------------------
// yg = y * silu(z); RMSNorm over D_INNER; bf16 in, bf16 out
// ---------------------------------------------------------------------------
__global__ __launch_bounds__(256) void gate_rmsnorm(const u16* __restrict__ z,
                                                    const u16* __restrict__ y,
                                                    const float* __restrict__ norm_w,
                                                    u16* __restrict__ yn)
{
    const int row = blockIdx.x;
    const int tid = threadIdx.x;
    const u16* zr = z + (size_t)row * D_INNER + tid * 8;
    const u16* yr = y + (size_t)row * D_INNER + tid * 8;
    u16*       o  = yn + (size_t)row * D_INNER + tid * 8;

    uint4 zv4 = *(const uint4*)zr;
    uint4 yv4 = *(const uint4*)yr;
    const u16* zp = (const u16*)&zv4;
    const u16* yp = (const u16*)&yv4;

    float vals[8];
    float ss = 0.f;
    #pragma unroll
    for (int j = 0; j < 8; ++j) {
        float zv = bf2f(zp[j]);
        float g  = bf2f(yp[j]) * (zv / (1.f + expf(-zv)));
        vals[j] = g;
        ss += g * g;
    }
    #pragma unroll
    for (int off = 32; off > 0; off >>= 1) ss += __shfl_down(ss, off);
    __shared__ float red[4];
    __shared__ float sscale;
    int wid = tid >> 6, lane = tid & 63;
    if (lane == 0) red[wid] = ss;
    __syncthreads();
    if (tid == 0)
        sscale = rsqrtf((red[0]+red[1]+red[2]+red[3]) / (float)D_INNER + 1e-5f);
    __syncthreads();
    float rms = sscale;
    const float4* nw = (const float4*)(norm_w + tid * 8);
    float4 w0 = nw[0], w1 = nw[1];
    float wv[8] = {w0.x,w0.y,w0.z,w0.w,w1.x,w1.y,w1.z,w1.w};
    u16 ov[8];
    #pragma unroll
    for (int j = 0; j < 8; ++j) ov[j] = f2bf(vals[j] * rms * wv[j]);
    *(uint4*)o = *(const uint4*)ov;
}

// ---------------------------------------------------------------------------
extern "C" void kernel_launch(void* const* d_in, const int* in_sizes, int n_in,
                              void* d_out, int out_size, void* d_ws, size_t ws_size,
                              hipStream_t stream)
{
    const float* u          = (const float*)d_in[0];
    const float* in_proj_w  = (const float*)d_in[1];
    const float* conv_w     = (const float*)d_in[2];
    const float* conv_b     = (const float*)d_in[3];
    const float* dt_bias    = (const float*)d_in[4];
    const float* A_log      = (const float*)d_in[5];
    const float* D_param    = (const float*)d_in[6];
    const float* norm_w     = (const float*)d_in[7];
    const float* out_proj_w = (const float*)d_in[8];
    float* out = (float*)d_out;

    char* w = (char*)d_ws;
    u16* z_bf     = (u16*)w;  w += (size_t)NROWS * D_INNER  * 2;   // 16.78 MB
    u16* xBC_bf   = (u16*)w;  w += (size_t)NROWS * CONV_DIM * 2;   // 17.83 MB
    u16* xconv_bf = (u16*)w;  w += (size_t)NROWS * CONV_DIM * 2;   // 17.83 MB
    u16* yb_bf    = (u16*)w;  w += (size_t)NROWS * D_INNER  * 2;   // 16.78 MB
    u16* dtraw_bf = (u16*)w;  w += (size_t)NROWS * NHEADS   * 2;   // 0.13 MB
    float* dtw    = (float*)w; w += (size_t)NROWS * NHEADS  * 4;   // 0.26 MB
    float* Tbuf   = (float*)w; w += (size_t)BATCH*NHEADS*NCHUNK * 4;
    u16* Sbuf     = (u16*)w;  w += (size_t)BATCH*NHEADS*NCHUNK*D_STATE*HEADDIM * 2; // 16.78 MB
    u16* u_bf     = (u16*)w;  w += (size_t)NROWS * D_MODEL  * 2;   // 8.39 MB
    u16* w_in_bf  = (u16*)w;  w += (size_t)NPAD  * D_MODEL  * 2;   // 8.91 MB
    u16* w_out_bf = (u16*)w;  w += (size_t)D_MODEL * D_INNER * 2;  // 4.19 MB
    u16* yn_bf    = xconv_bf;   // xconv dead after chunk_output

    // 0) all f32 -> bf16 conversions in one dispatch
    cvt_all<<<(CVT_N0+CVT_N1+CVT_N2 + 255)/256, 256, 0, stream>>>(
        u, in_proj_w, out_proj_w, u_bf, w_in_bf, w_out_bf);

    // 1) in_proj GEMM (8-wave 512-thr); grid 34 x 32 = 1088 (rect mapping)
    dim3 g1(NPAD/128, NROWS/128);
    gemm_in512<<<g1, 512, 0, stream>>>(u_bf, w_in_bf, D_MODEL,
                                       z_bf, D_INNER, D_INNER,
                                       xBC_bf, D_INNER + CONV_DIM, CONV_DIM,
                                       dtraw_bf, D_IN_PROJ, NHEADS);

    // 2) conv + SiLU + dt softplus (merged)
    int ntot = NCONV8 + NROWS * NHEADS;
    conv_silu_dt<<<(ntot + 255) / 256, 256, 0, stream>>>(
        xBC_bf, conv_w, conv_b, xconv_bf, dtraw_bf, dt_bias, dtw);

    // 3) chunked scan
    chunk_state<<<BATCH*NHEADS*NCHUNK, 256, 0, stream>>>(xconv_bf, dtw, A_log, Sbuf, Tbuf);
    chunk_seq_par<<<BATCH*NHEADS*8, 256, 0, stream>>>(Sbuf, Tbuf);
    chunk_output<<<BATCH*NHEADS*NCHUNK, 256, 0, stream>>>(xconv_bf, dtw, A_log, D_param,
                                                          Sbuf, yb_bf);

    // 4) gate + RMSNorm -> bf16
    gate_rmsnorm<<<NROWS, 256, 0, stream>>>(z_bf, yb_bf, norm_w, yn_bf);

    // 5) out_proj GEMM (8-wave 512-thr, LDS-staged f32 epilogue)
    dim3 g6(D_MODEL/128, NROWS/128);
    gemm_out512<<<g6, 512, 0, stream>>>(yn_bf, w_out_bf, D_INNER, out, D_MODEL);
}

// Round 20
// 205.108 us; speedup vs baseline: 1.0001x; 1.0001x over previous
//
#include <hip/hip_runtime.h>
#include <cstdint>
#include <cstddef>

#define D_MODEL   1024
#define D_STATE   64
#define D_CONV    4
#define HEADDIM   128
#define NHEADS    16
#define D_INNER   2048
#define CONV_DIM  2176          // D_INNER + 2*D_STATE
#define D_IN_PROJ 4240          // 2*D_INNER + 2*D_STATE + NHEADS
#define NPAD      4352          // D_IN_PROJ padded to multiple of 128
#define BATCH     2
#define SEQLEN    2048
#define NROWS     (BATCH*SEQLEN)   // 4096
#define CHUNK     64
#define NCHUNK    (SEQLEN/CHUNK)   // 32

using u16   = unsigned short;
using s16x8 = __attribute__((ext_vector_type(8))) short;   // 8 bf16 (4 VGPRs)
using f32x4 = __attribute__((ext_vector_type(4))) float;   // MFMA accumulator

// ---------------------------------------------------------------------------
// helpers
// ---------------------------------------------------------------------------
__device__ __forceinline__ u16 f2bf(float f) {
    union { float f; unsigned u; } v; v.f = f;
    unsigned r = v.u + 0x7fffu + ((v.u >> 16) & 1u);   // round-to-nearest-even
    return (u16)(r >> 16);
}
__device__ __forceinline__ float bf2f(u16 x) {
    union { unsigned u; float f; } v; v.u = ((unsigned)x) << 16;
    return v.f;
}

__device__ __forceinline__ void gload16(const u16* g, u16* l) {
    __builtin_amdgcn_global_load_lds(
        (const __attribute__((address_space(1))) unsigned int*)g,
        (__attribute__((address_space(3))) unsigned int*)l, 16, 0, 0);
}

__device__ __forceinline__ void cp8(const float* in, u16* out, int i) {
    const float4* p = (const float4*)(in + (size_t)i * 8);
    float4 a = p[0], b = p[1];
    u16 o[8] = {f2bf(a.x), f2bf(a.y), f2bf(a.z), f2bf(a.w),
                f2bf(b.x), f2bf(b.y), f2bf(b.z), f2bf(b.w)};
    *(uint4*)(out + (size_t)i * 8) = *(const uint4*)o;
}

// ---------------------------------------------------------------------------
// merged f32 -> bf16 conversion: u | in_proj_w (row-padded) | out_proj_w
// ---------------------------------------------------------------------------
#define CVT_N0 (NROWS*D_MODEL/8)      // 524288
#define CVT_N1 (NPAD*128)             // 557056
#define CVT_N2 (D_MODEL*D_INNER/8)    // 262144
__global__ __launch_bounds__(256) void cvt_all(
    const float* __restrict__ u, const float* __restrict__ w_in,
    const float* __restrict__ w_out,
    u16* __restrict__ u_bf, u16* __restrict__ w_in_bf, u16* __restrict__ w_out_bf)
{
    int i = blockIdx.x * 256 + threadIdx.x;
    if (i < CVT_N0) {
        cp8(u, u_bf, i);
    } else if (i < CVT_N0 + CVT_N1) {
        int j = i - CVT_N0;
        int row = j >> 7, seg = j & 127;
        u16 o[8] = {0,0,0,0,0,0,0,0};
        if (row < D_IN_PROJ) {
            const float4* p = (const float4*)(w_in + (size_t)row * D_MODEL + seg * 8);
            float4 a = p[0], b = p[1];
            o[0]=f2bf(a.x); o[1]=f2bf(a.y); o[2]=f2bf(a.z); o[3]=f2bf(a.w);
            o[4]=f2bf(b.x); o[5]=f2bf(b.y); o[6]=f2bf(b.z); o[7]=f2bf(b.w);
        }
        *(uint4*)(w_in_bf + (size_t)j * 8) = *(const uint4*)o;
    } else if (i < CVT_N0 + CVT_N1 + CVT_N2) {
        cp8(w_out, w_out_bf, i - CVT_N0 - CVT_N1);
    }
}

// ---------------------------------------------------------------------------
// in_proj GEMM: 128x128 tile, BK=64, 8 waves (512 thr), counted vmcnt(4),
// T2 swizzle, rect per-XCD mapping, LDS-staged coalesced epilogue.
// ---------------------------------------------------------------------------
#define CPITCH 136    // u16 pitch for epilogue tile (272B rows, 16B aligned)
__global__ __launch_bounds__(512) void gemm_in512(
    const u16* __restrict__ A, const u16* __restrict__ B, int K,
    u16* __restrict__ C0, int n1, int ld0,
    u16* __restrict__ C1, int n2, int ld1,
    u16* __restrict__ C2, int n3, int ld2)
{
    __shared__ u16 smem[4 * 128 * 64];          // 64 KB arena

    const int tid  = threadIdx.x;
    const int wid  = tid >> 6;               // 0..7
    const int lane = tid & 63;
    const int wm   = wid >> 2, wn = wid & 3; // 2 x 4 wave grid

    // rectangular XCD mapping: grid 34x32 = 1088 = 8 XCD x (8m x 17n)
    const int gx   = gridDim.x;                  // 34
    int orig = blockIdx.y * gx + blockIdx.x;     // 0..1087
    const int xcd = orig & 7;
    const int loc = orig >> 3;                   // 0..135
    const int mt  = (xcd >> 1) * 8  + (loc & 7); // 0..31
    const int nt  = (xcd & 1) * 17 + (loc >> 3); // 0..33
    const int m0 = mt * 128, n0 = nt * 128;

    const int lrow = lane >> 3;
    const int lseg = (lane & 7) ^ lrow;
    const u16* gA = A + (size_t)(m0 + lrow) * K + lseg * 8;
    const u16* gB = B + (size_t)(n0 + lrow) * K + lseg * 8;

    f32x4 acc[4][2];
    #pragma unroll
    for (int i = 0; i < 4; ++i)
        #pragma unroll
        for (int j = 0; j < 2; ++j)
            acc[i][j] = (f32x4){0.f, 0.f, 0.f, 0.f};

    const int fr = lane & 15, fq = lane >> 4;
    const int nstep = K >> 6;

    auto stage = [&](int buf, int k0) {
        u16* sAp = smem + buf * 8192;
        u16* sBp = smem + 16384 + buf * 8192;
        #pragma unroll
        for (int i = 0; i < 2; ++i) {
            const int r0 = (i * 8 + wid) * 8;
            gload16(gA + (size_t)r0 * K + k0, sAp + r0 * 64);
            gload16(gB + (size_t)r0 * K + k0, sBp + r0 * 64);
        }
    };

    stage(0, 0);
    int cur = 0;
    for (int step = 0; step < nstep; ++step) {
        if (step + 1 < nstep) {
            stage(cur ^ 1, (step + 1) * 64);
            asm volatile("s_waitcnt vmcnt(4)" ::: "memory");
        } else {
            asm volatile("s_waitcnt vmcnt(0)" ::: "memory");
        }
        __builtin_amdgcn_s_barrier();
        __builtin_amdgcn_sched_barrier(0);

        const u16* sAc = smem + cur * 8192;
        const u16* sBc = smem + 16384 + cur * 8192;
        #pragma unroll
        for (int ks = 0; ks < 2; ++ks) {
            s16x8 bfr[2];
            #pragma unroll
            for (int ni = 0; ni < 2; ++ni) {
                const int row = wn * 32 + ni * 16 + fr;
                const int bo = row * 128 + ((ks * 64 + fq * 16) ^ ((row & 7) << 4));
                bfr[ni] = *(const s16x8*)((const char*)sBc + bo);
            }
            #pragma unroll
            for (int mi = 0; mi < 4; ++mi) {
                const int row = wm * 64 + mi * 16 + fr;
                const int bo = row * 128 + ((ks * 64 + fq * 16) ^ ((row & 7) << 4));
                s16x8 af = *(const s16x8*)((const char*)sAc + bo);
                #pragma unroll
                for (int ni = 0; ni < 2; ++ni)
                    acc[mi][ni] = __builtin_amdgcn_mfma_f32_16x16x32_bf16(
                        af, bfr[ni], acc[mi][ni], 0, 0, 0);
            }
        }

        __builtin_amdgcn_sched_barrier(0);
        __builtin_amdgcn_s_barrier();
        cur ^= 1;
    }
    __builtin_amdgcn_sched_barrier(0);   // keep epilogue ds_writes after loop

    // ---- LDS-staged epilogue: frag layout -> row-linear -> 16B stores ----
    u16* sC = smem;                       // K-loop buffers dead now
    #pragma unroll
    for (int mi = 0; mi < 4; ++mi) {
        #pragma unroll
        for (int j = 0; j < 4; ++j) {
            const int rl = wm * 64 + mi * 16 + fq * 4 + j;
            #pragma unroll
            for (int ni = 0; ni < 2; ++ni) {
                const int cl = wn * 32 + ni * 16 + fr;
                sC[rl * CPITCH + cl] = f2bf(acc[mi][ni][j]);
            }
        }
    }
    __syncthreads();
    #pragma unroll
    for (int k2 = 0; k2 < 4; ++k2) {
        const int g  = tid + k2 * 512;        // 0..2047
        const int rl = g >> 4, cg = g & 15;
        uint4 v = *(const uint4*)&sC[rl * CPITCH + cg * 8];
        const int r = m0 + rl, c = n0 + cg * 8;
        if (c < n1)      *(uint4*)(C0 + (size_t)r * ld0 + c)        = v;
        else if (c < n2) *(uint4*)(C1 + (size_t)r * ld1 + (c - n1)) = v;
        else if (c < n3) *(uint4*)(C2 + (size_t)r * ld2 + (c - n2)) = v;
    }
}

// ---------------------------------------------------------------------------
// out_proj GEMM: 128x128 tile, BK=64, 8 waves (512 thr), counted vmcnt(4),
// LDS-staged f32 epilogue in two 64-row halves (coalesced 16B stores).
// ---------------------------------------------------------------------------
__global__ __launch_bounds__(512) void gemm_out512(
    const u16* __restrict__ A, const u16* __restrict__ B, int K,
    float* __restrict__ C, int N)
{
    __shared__ u16 smem[4 * 128 * 64];          // 64 KB arena

    const int tid  = threadIdx.x;
    const int wid  = tid >> 6;               // 0..7
    const int lane = tid & 63;
    const int wm   = wid >> 2, wn = wid & 3; // 2 x 4 wave grid

    const int gx   = gridDim.x;
    const int nwg  = gx * gridDim.y;
    const int cpx  = nwg >> 3;
    int orig = blockIdx.y * gx + blockIdx.x;
    int wg   = (orig & 7) * cpx + (orig >> 3);
    const int m0 = (wg / gx) * 128, n0 = (wg % gx) * 128;

    const int lrow = lane >> 3;
    const int lseg = (lane & 7) ^ lrow;
    const u16* gA = A + (size_t)(m0 + lrow) * K + lseg * 8;
    const u16* gB = B + (size_t)(n0 + lrow) * K + lseg * 8;

    f32x4 acc[4][2];
    #pragma unroll
    for (int i = 0; i < 4; ++i)
        #pragma unroll
        for (int j = 0; j < 2; ++j)
            acc[i][j] = (f32x4){0.f, 0.f, 0.f, 0.f};

    const int fr = lane & 15, fq = lane >> 4;
    const int nstep = K >> 6;

    auto stage = [&](int buf, int k0) {
        u16* sAp = smem + buf * 8192;
        u16* sBp = smem + 16384 + buf * 8192;
        #pragma unroll
        for (int i = 0; i < 2; ++i) {
            const int r0 = (i * 8 + wid) * 8;
            gload16(gA + (size_t)r0 * K + k0, sAp + r0 * 64);
            gload16(gB + (size_t)r0 * K + k0, sBp + r0 * 64);
        }
    };

    stage(0, 0);
    int cur = 0;
    for (int step = 0; step < nstep; ++step) {
        if (step + 1 < nstep) {
            stage(cur ^ 1, (step + 1) * 64);
            asm volatile("s_waitcnt vmcnt(4)" ::: "memory");
        } else {
            asm volatile("s_waitcnt vmcnt(0)" ::: "memory");
        }
        __builtin_amdgcn_s_barrier();
        __builtin_amdgcn_sched_barrier(0);

        const u16* sAc = smem + cur * 8192;
        const u16* sBc = smem + 16384 + cur * 8192;
        #pragma unroll
        for (int ks = 0; ks < 2; ++ks) {
            s16x8 bfr[2];
            #pragma unroll
            for (int ni = 0; ni < 2; ++ni) {
                const int row = wn * 32 + ni * 16 + fr;
                const int bo = row * 128 + ((ks * 64 + fq * 16) ^ ((row & 7) << 4));
                bfr[ni] = *(const s16x8*)((const char*)sBc + bo);
            }
            #pragma unroll
            for (int mi = 0; mi < 4; ++mi) {
                const int row = wm * 64 + mi * 16 + fr;
                const int bo = row * 128 + ((ks * 64 + fq * 16) ^ ((row & 7) << 4));
                s16x8 af = *(const s16x8*)((const char*)sAc + bo);
                #pragma unroll
                for (int ni = 0; ni < 2; ++ni)
                    acc[mi][ni] = __builtin_amdgcn_mfma_f32_16x16x32_bf16(
                        af, bfr[ni], acc[mi][ni], 0, 0, 0);
            }
        }

        __builtin_amdgcn_sched_barrier(0);
        __builtin_amdgcn_s_barrier();
        cur ^= 1;
    }
    __builtin_amdgcn_sched_barrier(0);

    // ---- LDS-staged f32 epilogue, two 64-row halves (pitch 132 f32) ----
    float* sCf = (float*)smem;            // 64x132x4 = 33.8 KB per half
    #pragma unroll
    for (int h2 = 0; h2 < 2; ++h2) {
        if (wm == h2) {
            #pragma unroll
            for (int mi = 0; mi < 4; ++mi)
                #pragma unroll
                for (int j = 0; j < 4; ++j) {
                    const int rl = mi * 16 + fq * 4 + j;        // 0..63
                    #pragma unroll
                    for (int ni = 0; ni < 2; ++ni) {
                        const int cl = wn * 32 + ni * 16 + fr;
                        sCf[rl * 132 + cl] = acc[mi][ni][j];
                    }
                }
        }
        __syncthreads();
        #pragma unroll
        for (int k2 = 0; k2 < 4; ++k2) {
            const int g  = tid + k2 * 512;    // 0..2047
            const int rl = g >> 5, cg = g & 31;
            float4 v = *(const float4*)&sCf[rl * 132 + cg * 4];
            *(float4*)(C + (size_t)(m0 + h2 * 64 + rl) * N + n0 + cg * 4) = v;
        }
        __syncthreads();
    }
}

// ---------------------------------------------------------------------------
// Depthwise causal conv(4)+bias+SiLU (8 ch/thread) and, in tail blocks,
// dt = softplus(dtraw + dt_bias)  (merged to save a dispatch).
// ---------------------------------------------------------------------------
#define NCONV8 (NROWS*(CONV_DIM/8))
__global__ __launch_bounds__(256) void conv_silu_dt(
    const u16* __restrict__ xBC, const float* __restrict__ conv_w,
    const float* __restrict__ conv_b, u16* __restrict__ xconv,
    const u16* __restrict__ dtraw, const float* __restrict__ dt_bias,
    float* __restrict__ dtw)
{
    int idx = blockIdx.x * 256 + threadIdx.x;
    if (idx < NCONV8) {
        int c8  = idx % (CONV_DIM / 8);
        int row = idx / (CONV_DIM / 8);     // b*SEQLEN + l
        int l   = row % SEQLEN;
        int b   = row / SEQLEN;
        int c0  = c8 * 8;
        const u16* src = xBC + (size_t)(b * SEQLEN) * CONV_DIM + c0;

        uint4 z4 = {0u, 0u, 0u, 0u};
        uint4 v3 = *(const uint4*)(src + (size_t)l * CONV_DIM);
        uint4 v2 = (l >= 1) ? *(const uint4*)(src + (size_t)(l-1) * CONV_DIM) : z4;
        uint4 v1 = (l >= 2) ? *(const uint4*)(src + (size_t)(l-2) * CONV_DIM) : z4;
        uint4 v0 = (l >= 3) ? *(const uint4*)(src + (size_t)(l-3) * CONV_DIM) : z4;
        const u16* p0 = (const u16*)&v0; const u16* p1 = (const u16*)&v1;
        const u16* p2 = (const u16*)&v2; const u16* p3 = (const u16*)&v3;

        u16 o[8];
        #pragma unroll
        for (int j = 0; j < 8; ++j) {
            const float4 w4 = *(const float4*)(conv_w + (size_t)(c0 + j) * 4);
            float acc = conv_b[c0 + j]
                      + bf2f(p0[j]) * w4.x + bf2f(p1[j]) * w4.y
                      + bf2f(p2[j]) * w4.z + bf2f(p3[j]) * w4.w;
            o[j] = f2bf(acc / (1.f + expf(-acc)));   // SiLU
        }
        *(uint4*)(xconv + (size_t)row * CONV_DIM + c0) = *(const uint4*)o;
    } else {
        int k = idx - NCONV8;
        if (k < NROWS * NHEADS) {
            int h = k & (NHEADS - 1);
            float v = bf2f(dtraw[k]) + dt_bias[h];
            dtw[k] = (v > 20.f) ? v : log1pf(expf(v));
        }
    }
}

// ---------------------------------------------------------------------------
// Phase A: chunk state.  S[n][p] = sum_s (W_s*B_s[n]) * x_s[p]  (bf16 out)
// sWB bf16 (8 KB): block LDS ~25 KB => 6 blocks/CU.
// ---------------------------------------------------------------------------
__global__ __launch_bounds__(256) void chunk_state(
    const u16* __restrict__ xconv, const float* __restrict__ dtw,
    const float* __restrict__ A_log, u16* __restrict__ Sbuf,
    float* __restrict__ Tbuf)
{
    const int blk = blockIdx.x;
    const int k  = blk & (NCHUNK-1);
    const int bh = blk >> 5;
    const int b  = bh >> 4, h = bh & 15;
    const int tid = threadIdx.x;
    const int wid = tid >> 6, lane = tid & 63;
    const float A = -expf(A_log[h]);

    __shared__ float sdt[CHUNK], sW[CHUNK], sT;
    __shared__ u16   sWB16[CHUNK * D_STATE];   // bf16, 128B rows, swz 16B units
    __shared__ u16   sX[CHUNK * HEADDIM];      // linear (DMA-staged)

    const int t0 = k * CHUNK;
    const u16* xc = xconv + (size_t)(b*SEQLEN + t0) * CONV_DIM;

    if (tid < CHUNK)
        sdt[tid] = dtw[(size_t)(b*SEQLEN + t0 + tid)*NHEADS + h];
    __syncthreads();
    if (tid < CHUNK) {
        float a = 0.f, pref = 0.f;
        for (int r = 0; r < CHUNK; ++r) {
            a += sdt[r] * A;
            if (r == tid) pref = a;
        }
        sW[tid] = __expf(a - pref) * sdt[tid];   // exp(T - L_s) * dt_s
        if (tid == 0) sT = a;
    }
    __syncthreads();

    // stage x via DMA: 4 calls/wave, 4 rows per call
    #pragma unroll
    for (int c = 0; c < 4; ++c) {
        const int r = wid * 16 + c * 4 + (lane >> 4);
        const int seg = lane & 15;
        gload16(xc + (size_t)r * CONV_DIM + h * HEADDIM + seg * 8,
                sX + (wid * 16 + c * 4) * HEADDIM);
    }
    // stage W*B (bf16, 128B rows, 16B-unit XOR swizzle)
    {
        const int s = tid >> 2, nb = tid & 3;
        const float wv = sW[s];
        uint4 b0 = *(const uint4*)(xc + (size_t)s*CONV_DIM + D_INNER + nb*16);
        uint4 b1 = *(const uint4*)(xc + (size_t)s*CONV_DIM + D_INNER + nb*16 + 8);
        const u16* pb0 = (const u16*)&b0; const u16* pb1 = (const u16*)&b1;
        u16 o[16];
        #pragma unroll
        for (int j = 0; j < 8; ++j) {
            o[j]     = f2bf(wv * bf2f(pb0[j]));
            o[8 + j] = f2bf(wv * bf2f(pb1[j]));
        }
        #pragma unroll
        for (int u2 = 0; u2 < 2; ++u2) {
            const int bo = s * 128 + ((nb * 32 + u2 * 16) ^ ((s & 7) << 4));
            *(uint4*)((char*)sWB16 + bo) = *(const uint4*)&o[u2 * 8];
        }
    }
    __syncthreads();

    // compute: thread (nn, pp) -> 4n x 8p
    const int nn = tid >> 4, pp = tid & 15;
    const int p0 = pp * 8, n0 = nn * 4;
    const int base16 = (nn >> 1) << 4;       // 16B granule of this nn's 8B read
    const int sub8   = (nn & 1) * 8;
    float acc[4][8];
    #pragma unroll
    for (int i = 0; i < 4; ++i)
        #pragma unroll
        for (int j = 0; j < 8; ++j) acc[i][j] = 0.f;

    for (int s = 0; s < CHUNK; ++s) {
        const int bo = s * 128 + ((base16 ^ ((s & 7) << 4)) + sub8);
        uint2 wv2 = *(const uint2*)((const char*)sWB16 + bo);
        const u16* wp = (const u16*)&wv2;
        const float w0f = bf2f(wp[0]), w1f = bf2f(wp[1]);
        const float w2f = bf2f(wp[2]), w3f = bf2f(wp[3]);
        uint4 xv = *(const uint4*)&sX[s * HEADDIM + p0];
        const u16* xp = (const u16*)&xv;
        #pragma unroll
        for (int j = 0; j < 8; ++j) {
            const float xf = bf2f(xp[j]);
            acc[0][j] += w0f * xf;
            acc[1][j] += w1f * xf;
            acc[2][j] += w2f * xf;
            acc[3][j] += w3f * xf;
        }
    }
    u16* So = Sbuf + ((size_t)bh*NCHUNK + k)*(D_STATE*HEADDIM);
    #pragma unroll
    for (int i = 0; i < 4; ++i) {
        u16 o[8];
        #pragma unroll
        for (int j = 0; j < 8; ++j) o[j] = f2bf(acc[i][j]);
        *(uint4*)(So + (size_t)(n0 + i) * HEADDIM + p0) = *(const uint4*)o;
    }
    if (tid == 0) Tbuf[bh*NCHUNK + k] = sT;
}

// ---------------------------------------------------------------------------
// Inter-chunk sequential pass (bf16 S, f32 accumulation), parallel over (n,p)
// ---------------------------------------------------------------------------
__global__ __launch_bounds__(256) void chunk_seq_par(u16* __restrict__ Sbuf,
                                                     const float* __restrict__ Tbuf)
{
    const int blk = blockIdx.x;           // 32 bh * 8 = 256 blocks
    const int bh  = blk >> 3;
    const int sub = blk & 7;
    __shared__ float seT[NCHUNK];
    if (threadIdx.x < NCHUNK)
        seT[threadIdx.x] = __expf(Tbuf[bh*NCHUNK + threadIdx.x]);
    __syncthreads();

    const int idx4 = sub * 256 + threadIdx.x;    // 4-elem index in [0,2048)
    u16* base = Sbuf + (size_t)bh*NCHUNK*(D_STATE*HEADDIM) + (size_t)idx4*4;
    float run[4];
    #pragma unroll
    for (int j = 0; j < 4; ++j) run[j] = 0.f;
    for (int k = 0; k < NCHUNK; ++k) {
        u16* p = base + (size_t)k * (D_STATE*HEADDIM);
        uint2 v = *(const uint2*)p;
        const u16* pv = (const u16*)&v;
        const float eT = seT[k];
        u16 o[4];
        #pragma unroll
        for (int j = 0; j < 4; ++j) {
            float tmp = bf2f(pv[j]);
            o[j] = f2bf(run[j]);
            run[j] = run[j] * eT + tmp;
        }
        *(uint2*)p = *(const uint2*)o;
    }
}

// ---------------------------------------------------------------------------
// Phase B: chunk outputs.  LDS squeezed to exactly 32 KB (5 blocks/CU):
// sdt/sL alias the first 512 B of sMt16 (dead until stage A writes);
// all later consumers preload to registers behind a barrier; seL recomputed.
// ---------------------------------------------------------------------------
__global__ __launch_bounds__(256) void chunk_output(
    const u16* __restrict__ xconv, const float* __restrict__ dtw,
    const float* __restrict__ A_log, const float* __restrict__ D_param,
    const u16* __restrict__ Sbuf, u16* __restrict__ y)
{
    const int blk = blockIdx.x;
    const int k  = blk & (NCHUNK-1);
    const int bh = blk >> 5;
    const int b  = bh >> 4, h = bh & 15;
    const int tid = threadIdx.x;
    const int wid = tid >> 6, lane = tid & 63;
    const float A  = -expf(A_log[h]);
    const float Dp = D_param[h];

    __shared__ u16 sMt16[(CHUNK + D_STATE) * CHUNK];  // bf16, swz, 128B rows (16 KB)
    __shared__ u16 sX[CHUNK * HEADDIM];               // linear, DMA-staged  (16 KB)
    float* sdt = (float*)sMt16;          // alias: bytes 0..255   (rows 0-1)
    float* sL  = sdt + CHUNK;            // alias: bytes 256..511 (rows 2-3)

    const int t0 = k * CHUNK;
    const u16* xc = xconv + (size_t)(b*SEQLEN + t0) * CONV_DIM;

    if (tid < CHUNK)
        sdt[tid] = dtw[(size_t)(b*SEQLEN + t0 + tid)*NHEADS + h];
    __syncthreads();
    if (tid < CHUNK) {
        float a = 0.f, pref = 0.f;
        for (int r = 0; r < CHUNK; ++r) {
            a += sdt[r] * A;
            if (r == tid) pref = a;
        }
        sL[tid] = pref;
    }
    __syncthreads();

    // ---- stage x via DMA (targets sX only; no alias conflict) ----
    #pragma unroll
    for (int c = 0; c < 4; ++c) {
        const int r = wid * 16 + c * 4 + (lane >> 4);
        const int seg = lane & 15;
        gload16(xc + (size_t)r * CONV_DIM + h * HEADDIM + seg * 8,
                sX + (wid * 16 + c * 4) * HEADDIM);
    }

    // ---- PRELOAD: read everything needed from sdt/sL into registers ----
    const int fr = lane & 15, fq = lane >> 4;
    float4 sL4 = *(const float4*)&sL[wid * 16 + fq * 4];
    const float Lt[4] = {sL4.x, sL4.y, sL4.z, sL4.w};
    float pre_L[4], pre_dt[4];
    #pragma unroll
    for (int sf = 0; sf < 4; ++sf) {
        const int s_row = sf * 16 + fr;
        pre_L[sf]  = sL[s_row];
        pre_dt[sf] = sdt[s_row];
    }
    const int tM = tid >> 2, nbM = tid & 3;           // Mext coords
    const float elM = __expf(sL[tM]);
    __syncthreads();     // all alias reads done before any sMt16 write

    // ---- G = C @ B^T via MFMA; decay epilogue -> sMt16 (bf16) ----
    {
        const int t_row = wid * 16 + fr;
        s16x8 cfrag[2];
        #pragma unroll
        for (int ks = 0; ks < 2; ++ks)
            cfrag[ks] = *(const s16x8*)(xc + (size_t)t_row*CONV_DIM + D_INNER + D_STATE
                                        + ks*32 + fq*8);

        #pragma unroll
        for (int sf = 0; sf < 4; ++sf) {
            const int s_row = sf * 16 + fr;
            f32x4 g = (f32x4){0.f, 0.f, 0.f, 0.f};
            #pragma unroll
            for (int ks = 0; ks < 2; ++ks) {
                s16x8 bfrag = *(const s16x8*)(xc + (size_t)s_row*CONV_DIM + D_INNER
                                              + ks*32 + fq*8);
                g = __builtin_amdgcn_mfma_f32_16x16x32_bf16(cfrag[ks], bfrag, g, 0, 0, 0);
            }
            const float Ls  = pre_L[sf];
            const float dts = pre_dt[sf];
            u16 o[4];
            #pragma unroll
            for (int r = 0; r < 4; ++r) {
                const int t = wid * 16 + fq * 4 + r;
                const float e = __expf(fminf(Lt[r] - Ls, 0.f)) * dts;
                o[r] = f2bf((s_row <= t) ? g[r] * e : 0.f);
            }
            const int bo2 = s_row * 128 + ((wid * 32 + fq * 8) ^ ((s_row & 7) << 4));
            *(uint2*)((char*)sMt16 + bo2) = *(const uint2*)o;
        }
    }

    // ---- Mext rows: sMt16[64+n][t] = exp(L_t) * C_t[n] ----
    {
        uint4 c0 = *(const uint4*)(xc + (size_t)tM*CONV_DIM + D_INNER + D_STATE + nbM*16);
        uint4 c1 = *(const uint4*)(xc + (size_t)tM*CONV_DIM + D_INNER + D_STATE + nbM*16 + 8);
        const u16* pc0 = (const u16*)&c0; const u16* pc1 = (const u16*)&c1;
        #pragma unroll
        for (int j = 0; j < 16; ++j) {
            const int n = nbM * 16 + j;
            const float v = elM * bf2f(j < 8 ? pc0[j] : pc1[j - 8]);
            const int bo2 = (CHUNK + n) * 128 + ((tM * 2) ^ ((n & 7) << 4));
            *(u16*)((char*)sMt16 + bo2) = f2bf(v);
        }
    }
    __syncthreads();

    // ---- Stage B: thread (tt, pp) -> 4t x 8p ----
    const int tt = tid >> 4, pp = tid & 15;
    const int p0 = pp * 8;
    float acc[4][8];
    #pragma unroll
    for (int i = 0; i < 4; ++i)
        #pragma unroll
        for (int j = 0; j < 8; ++j) acc[i][j] = 0.f;

    const int smax = tt * 4 + 4;      // causal: s <= t_max of this thread
    for (int s = 0; s < smax; ++s) {
        const int bo = s * 128 + ((tt * 8) ^ ((s & 7) << 4));
        uint2 mv = *(const uint2*)((const char*)sMt16 + bo);
        const u16* mp = (const u16*)&mv;
        const float m0f = bf2f(mp[0]), m1f = bf2f(mp[1]);
        const float m2f = bf2f(mp[2]), m3f = bf2f(mp[3]);
        uint4 xv = *(const uint4*)&sX[s * HEADDIM + p0];
        const u16* xp = (const u16*)&xv;
        #pragma unroll
        for (int j = 0; j < 8; ++j) {
            const float xf = bf2f(xp[j]);
            acc[0][j] += m0f * xf;
            acc[1][j] += m1f * xf;
            acc[2][j] += m2f * xf;
            acc[3][j] += m3f * xf;
        }
    }
    const u16* Sinit = Sbuf + ((size_t)bh*NCHUNK + k)*(D_STATE*HEADDIM);
    for (int n = 0; n < D_STATE; ++n) {
        const int bo = (CHUNK + n) * 128 + ((tt * 8) ^ ((n & 7) << 4));
        uint2 mv = *(const uint2*)((const char*)sMt16 + bo);
        const u16* mp = (const u16*)&mv;
        const float m0f = bf2f(mp[0]), m1f = bf2f(mp[1]);
        const float m2f = bf2f(mp[2]), m3f = bf2f(mp[3]);
        uint4 sv = *(const uint4*)(Sinit + (size_t)n * HEADDIM + p0);
        const u16* sp = (const u16*)&sv;
        #pragma unroll
        for (int j = 0; j < 8; ++j) {
            const float sf = bf2f(sp[j]);
            acc[0][j] += m0f * sf;
            acc[1][j] += m1f * sf;
            acc[2][j] += m2f * sf;
            acc[3][j] += m3f * sf;
        }
    }
    #pragma unroll
    for (int i = 0; i < 4; ++i) {
        const int t = tt * 4 + i;
        uint4 xv = *(const uint4*)&sX[t * HEADDIM + p0];
        const u16* xp = (const u16*)&xv;
        u16 o[8];
        #pragma unroll
        for (int j = 0; j < 8; ++j)
            o[j] = f2bf(acc[i][j] + Dp * bf2f(xp[j]));
        *(uint4*)(y + ((size_t)(b*SEQLEN + t0 + t))*D_INNER + h*HEADDIM + p0)
            = *(const uint4*)o;
    }
}

// ---------------------------------------------------------------------------
// yg = y * silu(z); RMSNorm over D_INNER; bf16 in, bf16 out
// ---------------------------------------------------------------------------
__global__ __launch_bounds__(256) void gate_rmsnorm(const u16* __restrict__ z,
                                                    const u16* __restrict__ y,
                                                    const float* __restrict__ norm_w,
                                                    u16* __restrict__ yn)
{
    const int row = blockIdx.x;
    const int tid = threadIdx.x;
    const u16* zr = z + (size_t)row * D_INNER + tid * 8;
    const u16* yr = y + (size_t)row * D_INNER + tid * 8;
    u16*       o  = yn + (size_t)row * D_INNER + tid * 8;

    uint4 zv4 = *(const uint4*)zr;
    uint4 yv4 = *(const uint4*)yr;
    const u16* zp = (const u16*)&zv4;
    const u16* yp = (const u16*)&yv4;

    float vals[8];
    float ss = 0.f;
    #pragma unroll
    for (int j = 0; j < 8; ++j) {
        float zv = bf2f(zp[j]);
        float g  = bf2f(yp[j]) * (zv / (1.f + expf(-zv)));
        vals[j] = g;
        ss += g * g;
    }
    #pragma unroll
    for (int off = 32; off > 0; off >>= 1) ss += __shfl_down(ss, off);
    __shared__ float red[4];
    __shared__ float sscale;
    int wid = tid >> 6, lane = tid & 63;
    if (lane == 0) red[wid] = ss;
    __syncthreads();
    if (tid == 0)
        sscale = rsqrtf((red[0]+red[1]+red[2]+red[3]) / (float)D_INNER + 1e-5f);
    __syncthreads();
    float rms = sscale;
    const float4* nw = (const float4*)(norm_w + tid * 8);
    float4 w0 = nw[0], w1 = nw[1];
    float wv[8] = {w0.x,w0.y,w0.z,w0.w,w1.x,w1.y,w1.z,w1.w};
    u16 ov[8];
    #pragma unroll
    for (int j = 0; j < 8; ++j) ov[j] = f2bf(vals[j] * rms * wv[j]);
    *(uint4*)o = *(const uint4*)ov;
}

// ---------------------------------------------------------------------------
extern "C" void kernel_launch(void* const* d_in, const int* in_sizes, int n_in,
                              void* d_out, int out_size, void* d_ws, size_t ws_size,
                              hipStream_t stream)
{
    const float* u          = (const float*)d_in[0];
    const float* in_proj_w  = (const float*)d_in[1];
    const float* conv_w     = (const float*)d_in[2];
    const float* conv_b     = (const float*)d_in[3];
    const float* dt_bias    = (const float*)d_in[4];
    const float* A_log      = (const float*)d_in[5];
    const float* D_param    = (const float*)d_in[6];
    const float* norm_w     = (const float*)d_in[7];
    const float* out_proj_w = (const float*)d_in[8];
    float* out = (float*)d_out;

    char* w = (char*)d_ws;
    u16* z_bf     = (u16*)w;  w += (size_t)NROWS * D_INNER  * 2;   // 16.78 MB
    u16* xBC_bf   = (u16*)w;  w += (size_t)NROWS * CONV_DIM * 2;   // 17.83 MB
    u16* xconv_bf = (u16*)w;  w += (size_t)NROWS * CONV_DIM * 2;   // 17.83 MB
    u16* yb_bf    = (u16*)w;  w += (size_t)NROWS * D_INNER  * 2;   // 16.78 MB
    u16* dtraw_bf = (u16*)w;  w += (size_t)NROWS * NHEADS   * 2;   // 0.13 MB
    float* dtw    = (float*)w; w += (size_t)NROWS * NHEADS  * 4;   // 0.26 MB
    float* Tbuf   = (float*)w; w += (size_t)BATCH*NHEADS*NCHUNK * 4;
    u16* Sbuf     = (u16*)w;  w += (size_t)BATCH*NHEADS*NCHUNK*D_STATE*HEADDIM * 2; // 16.78 MB
    u16* u_bf     = (u16*)w;  w += (size_t)NROWS * D_MODEL  * 2;   // 8.39 MB
    u16* w_in_bf  = (u16*)w;  w += (size_t)NPAD  * D_MODEL  * 2;   // 8.91 MB
    u16* w_out_bf = (u16*)w;  w += (size_t)D_MODEL * D_INNER * 2;  // 4.19 MB
    u16* yn_bf    = xconv_bf;   // xconv dead after chunk_output

    // 0) all f32 -> bf16 conversions in one dispatch
    cvt_all<<<(CVT_N0+CVT_N1+CVT_N2 + 255)/256, 256, 0, stream>>>(
        u, in_proj_w, out_proj_w, u_bf, w_in_bf, w_out_bf);

    // 1) in_proj GEMM (8-wave 512-thr); grid 34 x 32 = 1088 (rect mapping)
    dim3 g1(NPAD/128, NROWS/128);
    gemm_in512<<<g1, 512, 0, stream>>>(u_bf, w_in_bf, D_MODEL,
                                       z_bf, D_INNER, D_INNER,
                                       xBC_bf, D_INNER + CONV_DIM, CONV_DIM,
                                       dtraw_bf, D_IN_PROJ, NHEADS);

    // 2) conv + SiLU + dt softplus (merged)
    int ntot = NCONV8 + NROWS * NHEADS;
    conv_silu_dt<<<(ntot + 255) / 256, 256, 0, stream>>>(
        xBC_bf, conv_w, conv_b, xconv_bf, dtraw_bf, dt_bias, dtw);

    // 3) chunked scan
    chunk_state<<<BATCH*NHEADS*NCHUNK, 256, 0, stream>>>(xconv_bf, dtw, A_log, Sbuf, Tbuf);
    chunk_seq_par<<<BATCH*NHEADS*8, 256, 0, stream>>>(Sbuf, Tbuf);
    chunk_output<<<BATCH*NHEADS*NCHUNK, 256, 0, stream>>>(xconv_bf, dtw, A_log, D_param,
                                                          Sbuf, yb_bf);

    // 4) gate + RMSNorm -> bf16
    gate_rmsnorm<<<NROWS, 256, 0, stream>>>(z_bf, yb_bf, norm_w, yn_bf);

    // 5) out_proj GEMM (8-wave 512-thr, LDS-staged f32 epilogue)
    dim3 g6(D_MODEL/128, NROWS/128);
    gemm_out512<<<g6, 512, 0, stream>>>(yn_bf, w_out_bf, D_INNER, out, D_MODEL);
}

// Round 21
// 202.909 us; speedup vs baseline: 1.0109x; 1.0108x over previous
//
#include <hip/hip_runtime.h>
#include <cstdint>
#include <cstddef>

#define D_MODEL   1024
#define D_STATE   64
#define D_CONV    4
#define HEADDIM   128
#define NHEADS    16
#define D_INNER   2048
#define CONV_DIM  2176          // D_INNER + 2*D_STATE
#define D_IN_PROJ 4240          // 2*D_INNER + 2*D_STATE + NHEADS
#define NPAD      4352          // D_IN_PROJ padded to multiple of 128
#define BATCH     2
#define SEQLEN    2048
#define NROWS     (BATCH*SEQLEN)   // 4096
#define CHUNK     64
#define NCHUNK    (SEQLEN/CHUNK)   // 32

using u16   = unsigned short;
using s16x8 = __attribute__((ext_vector_type(8))) short;   // 8 bf16 (4 VGPRs)
using f32x4 = __attribute__((ext_vector_type(4))) float;   // MFMA accumulator

// ---------------------------------------------------------------------------
// helpers
// ---------------------------------------------------------------------------
__device__ __forceinline__ u16 f2bf(float f) {
    union { float f; unsigned u; } v; v.f = f;
    unsigned r = v.u + 0x7fffu + ((v.u >> 16) & 1u);   // round-to-nearest-even
    return (u16)(r >> 16);
}
__device__ __forceinline__ float bf2f(u16 x) {
    union { unsigned u; float f; } v; v.u = ((unsigned)x) << 16;
    return v.f;
}

__device__ __forceinline__ void gload16(const u16* g, u16* l) {
    __builtin_amdgcn_global_load_lds(
        (const __attribute__((address_space(1))) unsigned int*)g,
        (__attribute__((address_space(3))) unsigned int*)l, 16, 0, 0);
}

__device__ __forceinline__ void cp8(const float* in, u16* out, int i) {
    const float4* p = (const float4*)(in + (size_t)i * 8);
    float4 a = p[0], b = p[1];
    u16 o[8] = {f2bf(a.x), f2bf(a.y), f2bf(a.z), f2bf(a.w),
                f2bf(b.x), f2bf(b.y), f2bf(b.z), f2bf(b.w)};
    *(uint4*)(out + (size_t)i * 8) = *(const uint4*)o;
}

// ---------------------------------------------------------------------------
// merged f32 -> bf16 conversion: u | in_proj_w (row-padded) | out_proj_w
// ---------------------------------------------------------------------------
#define CVT_N0 (NROWS*D_MODEL/8)      // 524288
#define CVT_N1 (NPAD*128)             // 557056
#define CVT_N2 (D_MODEL*D_INNER/8)    // 262144
__global__ __launch_bounds__(256) void cvt_all(
    const float* __restrict__ u, const float* __restrict__ w_in,
    const float* __restrict__ w_out,
    u16* __restrict__ u_bf, u16* __restrict__ w_in_bf, u16* __restrict__ w_out_bf)
{
    int i = blockIdx.x * 256 + threadIdx.x;
    if (i < CVT_N0) {
        cp8(u, u_bf, i);
    } else if (i < CVT_N0 + CVT_N1) {
        int j = i - CVT_N0;
        int row = j >> 7, seg = j & 127;
        u16 o[8] = {0,0,0,0,0,0,0,0};
        if (row < D_IN_PROJ) {
            const float4* p = (const float4*)(w_in + (size_t)row * D_MODEL + seg * 8);
            float4 a = p[0], b = p[1];
            o[0]=f2bf(a.x); o[1]=f2bf(a.y); o[2]=f2bf(a.z); o[3]=f2bf(a.w);
            o[4]=f2bf(b.x); o[5]=f2bf(b.y); o[6]=f2bf(b.z); o[7]=f2bf(b.w);
        }
        *(uint4*)(w_in_bf + (size_t)j * 8) = *(const uint4*)o;
    } else if (i < CVT_N0 + CVT_N1 + CVT_N2) {
        cp8(w_out, w_out_bf, i - CVT_N0 - CVT_N1);
    }
}

// ---------------------------------------------------------------------------
// in_proj GEMM: 128x128 tile, BK=64, 8 waves (512 thr), counted vmcnt(4),
// T2 swizzle, rect per-XCD mapping, LDS-staged coalesced epilogue.
// ---------------------------------------------------------------------------
#define CPITCH 136    // u16 pitch for epilogue tile (272B rows, 16B aligned)
__global__ __launch_bounds__(512) void gemm_in512(
    const u16* __restrict__ A, const u16* __restrict__ B, int K,
    u16* __restrict__ C0, int n1, int ld0,
    u16* __restrict__ C1, int n2, int ld1,
    u16* __restrict__ C2, int n3, int ld2)
{
    __shared__ u16 smem[4 * 128 * 64];          // 64 KB arena

    const int tid  = threadIdx.x;
    const int wid  = tid >> 6;               // 0..7
    const int lane = tid & 63;
    const int wm   = wid >> 2, wn = wid & 3; // 2 x 4 wave grid

    // rectangular XCD mapping: grid 34x32 = 1088 = 8 XCD x (8m x 17n)
    const int gx   = gridDim.x;                  // 34
    int orig = blockIdx.y * gx + blockIdx.x;     // 0..1087
    const int xcd = orig & 7;
    const int loc = orig >> 3;                   // 0..135
    const int mt  = (xcd >> 1) * 8  + (loc & 7); // 0..31
    const int nt  = (xcd & 1) * 17 + (loc >> 3); // 0..33
    const int m0 = mt * 128, n0 = nt * 128;

    const int lrow = lane >> 3;
    const int lseg = (lane & 7) ^ lrow;
    const u16* gA = A + (size_t)(m0 + lrow) * K + lseg * 8;
    const u16* gB = B + (size_t)(n0 + lrow) * K + lseg * 8;

    f32x4 acc[4][2];
    #pragma unroll
    for (int i = 0; i < 4; ++i)
        #pragma unroll
        for (int j = 0; j < 2; ++j)
            acc[i][j] = (f32x4){0.f, 0.f, 0.f, 0.f};

    const int fr = lane & 15, fq = lane >> 4;
    const int nstep = K >> 6;

    auto stage = [&](int buf, int k0) {
        u16* sAp = smem + buf * 8192;
        u16* sBp = smem + 16384 + buf * 8192;
        #pragma unroll
        for (int i = 0; i < 2; ++i) {
            const int r0 = (i * 8 + wid) * 8;
            gload16(gA + (size_t)r0 * K + k0, sAp + r0 * 64);
            gload16(gB + (size_t)r0 * K + k0, sBp + r0 * 64);
        }
    };

    stage(0, 0);
    int cur = 0;
    for (int step = 0; step < nstep; ++step) {
        if (step + 1 < nstep) {
            stage(cur ^ 1, (step + 1) * 64);
            asm volatile("s_waitcnt vmcnt(4)" ::: "memory");
        } else {
            asm volatile("s_waitcnt vmcnt(0)" ::: "memory");
        }
        __builtin_amdgcn_s_barrier();
        __builtin_amdgcn_sched_barrier(0);

        const u16* sAc = smem + cur * 8192;
        const u16* sBc = smem + 16384 + cur * 8192;
        #pragma unroll
        for (int ks = 0; ks < 2; ++ks) {
            s16x8 bfr[2];
            #pragma unroll
            for (int ni = 0; ni < 2; ++ni) {
                const int row = wn * 32 + ni * 16 + fr;
                const int bo = row * 128 + ((ks * 64 + fq * 16) ^ ((row & 7) << 4));
                bfr[ni] = *(const s16x8*)((const char*)sBc + bo);
            }
            #pragma unroll
            for (int mi = 0; mi < 4; ++mi) {
                const int row = wm * 64 + mi * 16 + fr;
                const int bo = row * 128 + ((ks * 64 + fq * 16) ^ ((row & 7) << 4));
                s16x8 af = *(const s16x8*)((const char*)sAc + bo);
                #pragma unroll
                for (int ni = 0; ni < 2; ++ni)
                    acc[mi][ni] = __builtin_amdgcn_mfma_f32_16x16x32_bf16(
                        af, bfr[ni], acc[mi][ni], 0, 0, 0);
            }
        }

        __builtin_amdgcn_sched_barrier(0);
        __builtin_amdgcn_s_barrier();
        cur ^= 1;
    }
    __builtin_amdgcn_sched_barrier(0);   // keep epilogue ds_writes after loop

    // ---- LDS-staged epilogue: frag layout -> row-linear -> 16B stores ----
    u16* sC = smem;                       // K-loop buffers dead now
    #pragma unroll
    for (int mi = 0; mi < 4; ++mi) {
        #pragma unroll
        for (int j = 0; j < 4; ++j) {
            const int rl = wm * 64 + mi * 16 + fq * 4 + j;
            #pragma unroll
            for (int ni = 0; ni < 2; ++ni) {
                const int cl = wn * 32 + ni * 16 + fr;
                sC[rl * CPITCH + cl] = f2bf(acc[mi][ni][j]);
            }
        }
    }
    __syncthreads();
    #pragma unroll
    for (int k2 = 0; k2 < 4; ++k2) {
        const int g  = tid + k2 * 512;        // 0..2047
        const int rl = g >> 4, cg = g & 15;
        uint4 v = *(const uint4*)&sC[rl * CPITCH + cg * 8];
        const int r = m0 + rl, c = n0 + cg * 8;
        if (c < n1)      *(uint4*)(C0 + (size_t)r * ld0 + c)        = v;
        else if (c < n2) *(uint4*)(C1 + (size_t)r * ld1 + (c - n1)) = v;
        else if (c < n3) *(uint4*)(C2 + (size_t)r * ld2 + (c - n2)) = v;
    }
}

// ---------------------------------------------------------------------------
// out_proj GEMM: 128x128 tile, BK=64, 8 waves (512 thr), counted vmcnt(4),
// LDS-staged f32 epilogue in two 64-row halves (coalesced 16B stores).
// ---------------------------------------------------------------------------
__global__ __launch_bounds__(512) void gemm_out512(
    const u16* __restrict__ A, const u16* __restrict__ B, int K,
    float* __restrict__ C, int N)
{
    __shared__ u16 smem[4 * 128 * 64];          // 64 KB arena

    const int tid  = threadIdx.x;
    const int wid  = tid >> 6;               // 0..7
    const int lane = tid & 63;
    const int wm   = wid >> 2, wn = wid & 3; // 2 x 4 wave grid

    const int gx   = gridDim.x;
    const int nwg  = gx * gridDim.y;
    const int cpx  = nwg >> 3;
    int orig = blockIdx.y * gx + blockIdx.x;
    int wg   = (orig & 7) * cpx + (orig >> 3);
    const int m0 = (wg / gx) * 128, n0 = (wg % gx) * 128;

    const int lrow = lane >> 3;
    const int lseg = (lane & 7) ^ lrow;
    const u16* gA = A + (size_t)(m0 + lrow) * K + lseg * 8;
    const u16* gB = B + (size_t)(n0 + lrow) * K + lseg * 8;

    f32x4 acc[4][2];
    #pragma unroll
    for (int i = 0; i < 4; ++i)
        #pragma unroll
        for (int j = 0; j < 2; ++j)
            acc[i][j] = (f32x4){0.f, 0.f, 0.f, 0.f};

    const int fr = lane & 15, fq = lane >> 4;
    const int nstep = K >> 6;

    auto stage = [&](int buf, int k0) {
        u16* sAp = smem + buf * 8192;
        u16* sBp = smem + 16384 + buf * 8192;
        #pragma unroll
        for (int i = 0; i < 2; ++i) {
            const int r0 = (i * 8 + wid) * 8;
            gload16(gA + (size_t)r0 * K + k0, sAp + r0 * 64);
            gload16(gB + (size_t)r0 * K + k0, sBp + r0 * 64);
        }
    };

    stage(0, 0);
    int cur = 0;
    for (int step = 0; step < nstep; ++step) {
        if (step + 1 < nstep) {
            stage(cur ^ 1, (step + 1) * 64);
            asm volatile("s_waitcnt vmcnt(4)" ::: "memory");
        } else {
            asm volatile("s_waitcnt vmcnt(0)" ::: "memory");
        }
        __builtin_amdgcn_s_barrier();
        __builtin_amdgcn_sched_barrier(0);

        const u16* sAc = smem + cur * 8192;
        const u16* sBc = smem + 16384 + cur * 8192;
        #pragma unroll
        for (int ks = 0; ks < 2; ++ks) {
            s16x8 bfr[2];
            #pragma unroll
            for (int ni = 0; ni < 2; ++ni) {
                const int row = wn * 32 + ni * 16 + fr;
                const int bo = row * 128 + ((ks * 64 + fq * 16) ^ ((row & 7) << 4));
                bfr[ni] = *(const s16x8*)((const char*)sBc + bo);
            }
            #pragma unroll
            for (int mi = 0; mi < 4; ++mi) {
                const int row = wm * 64 + mi * 16 + fr;
                const int bo = row * 128 + ((ks * 64 + fq * 16) ^ ((row & 7) << 4));
                s16x8 af = *(const s16x8*)((const char*)sAc + bo);
                #pragma unroll
                for (int ni = 0; ni < 2; ++ni)
                    acc[mi][ni] = __builtin_amdgcn_mfma_f32_16x16x32_bf16(
                        af, bfr[ni], acc[mi][ni], 0, 0, 0);
            }
        }

        __builtin_amdgcn_sched_barrier(0);
        __builtin_amdgcn_s_barrier();
        cur ^= 1;
    }
    __builtin_amdgcn_sched_barrier(0);

    // ---- LDS-staged f32 epilogue, two 64-row halves (pitch 132 f32) ----
    float* sCf = (float*)smem;            // 64x132x4 = 33.8 KB per half
    #pragma unroll
    for (int h2 = 0; h2 < 2; ++h2) {
        if (wm == h2) {
            #pragma unroll
            for (int mi = 0; mi < 4; ++mi)
                #pragma unroll
                for (int j = 0; j < 4; ++j) {
                    const int rl = mi * 16 + fq * 4 + j;        // 0..63
                    #pragma unroll
                    for (int ni = 0; ni < 2; ++ni) {
                        const int cl = wn * 32 + ni * 16 + fr;
                        sCf[rl * 132 + cl] = acc[mi][ni][j];
                    }
                }
        }
        __syncthreads();
        #pragma unroll
        for (int k2 = 0; k2 < 4; ++k2) {
            const int g  = tid + k2 * 512;    // 0..2047
            const int rl = g >> 5, cg = g & 31;
            float4 v = *(const float4*)&sCf[rl * 132 + cg * 4];
            *(float4*)(C + (size_t)(m0 + h2 * 64 + rl) * N + n0 + cg * 4) = v;
        }
        __syncthreads();
    }
}

// ---------------------------------------------------------------------------
// Depthwise causal conv(4)+bias+SiLU (8 ch/thread) and, in tail blocks,
// dt = softplus(dtraw + dt_bias)  (merged to save a dispatch).
// ---------------------------------------------------------------------------
#define NCONV8 (NROWS*(CONV_DIM/8))
__global__ __launch_bounds__(256) void conv_silu_dt(
    const u16* __restrict__ xBC, const float* __restrict__ conv_w,
    const float* __restrict__ conv_b, u16* __restrict__ xconv,
    const u16* __restrict__ dtraw, const float* __restrict__ dt_bias,
    float* __restrict__ dtw)
{
    int idx = blockIdx.x * 256 + threadIdx.x;
    if (idx < NCONV8) {
        int c8  = idx % (CONV_DIM / 8);
        int row = idx / (CONV_DIM / 8);     // b*SEQLEN + l
        int l   = row % SEQLEN;
        int b   = row / SEQLEN;
        int c0  = c8 * 8;
        const u16* src = xBC + (size_t)(b * SEQLEN) * CONV_DIM + c0;

        uint4 z4 = {0u, 0u, 0u, 0u};
        uint4 v3 = *(const uint4*)(src + (size_t)l * CONV_DIM);
        uint4 v2 = (l >= 1) ? *(const uint4*)(src + (size_t)(l-1) * CONV_DIM) : z4;
        uint4 v1 = (l >= 2) ? *(const uint4*)(src + (size_t)(l-2) * CONV_DIM) : z4;
        uint4 v0 = (l >= 3) ? *(const uint4*)(src + (size_t)(l-3) * CONV_DIM) : z4;
        const u16* p0 = (const u16*)&v0; const u16* p1 = (const u16*)&v1;
        const u16* p2 = (const u16*)&v2; const u16* p3 = (const u16*)&v3;

        u16 o[8];
        #pragma unroll
        for (int j = 0; j < 8; ++j) {
            const float4 w4 = *(const float4*)(conv_w + (size_t)(c0 + j) * 4);
            float acc = conv_b[c0 + j]
                      + bf2f(p0[j]) * w4.x + bf2f(p1[j]) * w4.y
                      + bf2f(p2[j]) * w4.z + bf2f(p3[j]) * w4.w;
            o[j] = f2bf(acc / (1.f + expf(-acc)));   // SiLU
        }
        *(uint4*)(xconv + (size_t)row * CONV_DIM + c0) = *(const uint4*)o;
    } else {
        int k = idx - NCONV8;
        if (k < NROWS * NHEADS) {
            int h = k & (NHEADS - 1);
            float v = bf2f(dtraw[k]) + dt_bias[h];
            dtw[k] = (v > 20.f) ? v : log1pf(expf(v));
        }
    }
}

// ---------------------------------------------------------------------------
// Phase A: chunk state.  S[n][p] = sum_s (W_s*B_s[n]) * x_s[p]  (bf16 out)
// sWB bf16 (8 KB).  Inner loop unrolled 4x for LDS-load batching.
// ---------------------------------------------------------------------------
__global__ __launch_bounds__(256) void chunk_state(
    const u16* __restrict__ xconv, const float* __restrict__ dtw,
    const float* __restrict__ A_log, u16* __restrict__ Sbuf,
    float* __restrict__ Tbuf)
{
    const int blk = blockIdx.x;
    const int k  = blk & (NCHUNK-1);
    const int bh = blk >> 5;
    const int b  = bh >> 4, h = bh & 15;
    const int tid = threadIdx.x;
    const int wid = tid >> 6, lane = tid & 63;
    const float A = -expf(A_log[h]);

    __shared__ float sdt[CHUNK], sW[CHUNK], sT;
    __shared__ u16   sWB16[CHUNK * D_STATE];   // bf16, 128B rows, swz 16B units
    __shared__ u16   sX[CHUNK * HEADDIM];      // linear (DMA-staged)

    const int t0 = k * CHUNK;
    const u16* xc = xconv + (size_t)(b*SEQLEN + t0) * CONV_DIM;

    if (tid < CHUNK)
        sdt[tid] = dtw[(size_t)(b*SEQLEN + t0 + tid)*NHEADS + h];
    __syncthreads();
    if (tid < CHUNK) {
        float a = 0.f, pref = 0.f;
        for (int r = 0; r < CHUNK; ++r) {
            a += sdt[r] * A;
            if (r == tid) pref = a;
        }
        sW[tid] = __expf(a - pref) * sdt[tid];   // exp(T - L_s) * dt_s
        if (tid == 0) sT = a;
    }
    __syncthreads();

    // stage x via DMA: 4 calls/wave, 4 rows per call
    #pragma unroll
    for (int c = 0; c < 4; ++c) {
        const int r = wid * 16 + c * 4 + (lane >> 4);
        const int seg = lane & 15;
        gload16(xc + (size_t)r * CONV_DIM + h * HEADDIM + seg * 8,
                sX + (wid * 16 + c * 4) * HEADDIM);
    }
    // stage W*B (bf16, 128B rows, 16B-unit XOR swizzle)
    {
        const int s = tid >> 2, nb = tid & 3;
        const float wv = sW[s];
        uint4 b0 = *(const uint4*)(xc + (size_t)s*CONV_DIM + D_INNER + nb*16);
        uint4 b1 = *(const uint4*)(xc + (size_t)s*CONV_DIM + D_INNER + nb*16 + 8);
        const u16* pb0 = (const u16*)&b0; const u16* pb1 = (const u16*)&b1;
        u16 o[16];
        #pragma unroll
        for (int j = 0; j < 8; ++j) {
            o[j]     = f2bf(wv * bf2f(pb0[j]));
            o[8 + j] = f2bf(wv * bf2f(pb1[j]));
        }
        #pragma unroll
        for (int u2 = 0; u2 < 2; ++u2) {
            const int bo = s * 128 + ((nb * 32 + u2 * 16) ^ ((s & 7) << 4));
            *(uint4*)((char*)sWB16 + bo) = *(const uint4*)&o[u2 * 8];
        }
    }
    __syncthreads();

    // compute: thread (nn, pp) -> 4n x 8p
    const int nn = tid >> 4, pp = tid & 15;
    const int p0 = pp * 8, n0 = nn * 4;
    const int base16 = (nn >> 1) << 4;       // 16B granule of this nn's 8B read
    const int sub8   = (nn & 1) * 8;
    float acc[4][8];
    #pragma unroll
    for (int i = 0; i < 4; ++i)
        #pragma unroll
        for (int j = 0; j < 8; ++j) acc[i][j] = 0.f;

    for (int sb = 0; sb < CHUNK; sb += 4) {
        #pragma unroll
        for (int si = 0; si < 4; ++si) {
            const int s = sb + si;
            const int bo = s * 128 + ((base16 ^ ((s & 7) << 4)) + sub8);
            uint2 wv2 = *(const uint2*)((const char*)sWB16 + bo);
            const u16* wp = (const u16*)&wv2;
            const float w0f = bf2f(wp[0]), w1f = bf2f(wp[1]);
            const float w2f = bf2f(wp[2]), w3f = bf2f(wp[3]);
            uint4 xv = *(const uint4*)&sX[s * HEADDIM + p0];
            const u16* xp = (const u16*)&xv;
            #pragma unroll
            for (int j = 0; j < 8; ++j) {
                const float xf = bf2f(xp[j]);
                acc[0][j] += w0f * xf;
                acc[1][j] += w1f * xf;
                acc[2][j] += w2f * xf;
                acc[3][j] += w3f * xf;
            }
        }
    }
    u16* So = Sbuf + ((size_t)bh*NCHUNK + k)*(D_STATE*HEADDIM);
    #pragma unroll
    for (int i = 0; i < 4; ++i) {
        u16 o[8];
        #pragma unroll
        for (int j = 0; j < 8; ++j) o[j] = f2bf(acc[i][j]);
        *(uint4*)(So + (size_t)(n0 + i) * HEADDIM + p0) = *(const uint4*)o;
    }
    if (tid == 0) Tbuf[bh*NCHUNK + k] = sT;
}

// ---------------------------------------------------------------------------
// Inter-chunk sequential pass (bf16 S, f32 accumulation), parallel over (n,p)
// ---------------------------------------------------------------------------
__global__ __launch_bounds__(256) void chunk_seq_par(u16* __restrict__ Sbuf,
                                                     const float* __restrict__ Tbuf)
{
    const int blk = blockIdx.x;           // 32 bh * 8 = 256 blocks
    const int bh  = blk >> 3;
    const int sub = blk & 7;
    __shared__ float seT[NCHUNK];
    if (threadIdx.x < NCHUNK)
        seT[threadIdx.x] = __expf(Tbuf[bh*NCHUNK + threadIdx.x]);
    __syncthreads();

    const int idx4 = sub * 256 + threadIdx.x;    // 4-elem index in [0,2048)
    u16* base = Sbuf + (size_t)bh*NCHUNK*(D_STATE*HEADDIM) + (size_t)idx4*4;
    float run[4];
    #pragma unroll
    for (int j = 0; j < 4; ++j) run[j] = 0.f;
    for (int k = 0; k < NCHUNK; ++k) {
        u16* p = base + (size_t)k * (D_STATE*HEADDIM);
        uint2 v = *(const uint2*)p;
        const u16* pv = (const u16*)&v;
        const float eT = seT[k];
        u16 o[4];
        #pragma unroll
        for (int j = 0; j < 4; ++j) {
            float tmp = bf2f(pv[j]);
            o[j] = f2bf(run[j]);
            run[j] = run[j] * eT + tmp;
        }
        *(uint2*)p = *(const uint2*)o;
    }
}

// ---------------------------------------------------------------------------
// Phase B: chunk outputs.  32 KB LDS; stage-B loops unrolled for load
// pipelining (X loop exact 4x nest; Sinit loop unroll 8 to batch globals).
// ---------------------------------------------------------------------------
__global__ __launch_bounds__(256) void chunk_output(
    const u16* __restrict__ xconv, const float* __restrict__ dtw,
    const float* __restrict__ A_log, const float* __restrict__ D_param,
    const u16* __restrict__ Sbuf, u16* __restrict__ y)
{
    const int blk = blockIdx.x;
    const int k  = blk & (NCHUNK-1);
    const int bh = blk >> 5;
    const int b  = bh >> 4, h = bh & 15;
    const int tid = threadIdx.x;
    const int wid = tid >> 6, lane = tid & 63;
    const float A  = -expf(A_log[h]);
    const float Dp = D_param[h];

    __shared__ u16 sMt16[(CHUNK + D_STATE) * CHUNK];  // bf16, swz, 128B rows (16 KB)
    __shared__ u16 sX[CHUNK * HEADDIM];               // linear, DMA-staged  (16 KB)
    float* sdt = (float*)sMt16;          // alias: bytes 0..255   (rows 0-1)
    float* sL  = sdt + CHUNK;            // alias: bytes 256..511 (rows 2-3)

    const int t0 = k * CHUNK;
    const u16* xc = xconv + (size_t)(b*SEQLEN + t0) * CONV_DIM;

    if (tid < CHUNK)
        sdt[tid] = dtw[(size_t)(b*SEQLEN + t0 + tid)*NHEADS + h];
    __syncthreads();
    if (tid < CHUNK) {
        float a = 0.f, pref = 0.f;
        for (int r = 0; r < CHUNK; ++r) {
            a += sdt[r] * A;
            if (r == tid) pref = a;
        }
        sL[tid] = pref;
    }
    __syncthreads();

    // ---- stage x via DMA (targets sX only; no alias conflict) ----
    #pragma unroll
    for (int c = 0; c < 4; ++c) {
        const int r = wid * 16 + c * 4 + (lane >> 4);
        const int seg = lane & 15;
        gload16(xc + (size_t)r * CONV_DIM + h * HEADDIM + seg * 8,
                sX + (wid * 16 + c * 4) * HEADDIM);
    }

    // ---- PRELOAD: read everything needed from sdt/sL into registers ----
    const int fr = lane & 15, fq = lane >> 4;
    float4 sL4 = *(const float4*)&sL[wid * 16 + fq * 4];
    const float Lt[4] = {sL4.x, sL4.y, sL4.z, sL4.w};
    float pre_L[4], pre_dt[4];
    #pragma unroll
    for (int sf = 0; sf < 4; ++sf) {
        const int s_row = sf * 16 + fr;
        pre_L[sf]  = sL[s_row];
        pre_dt[sf] = sdt[s_row];
    }
    const int tM = tid >> 2, nbM = tid & 3;           // Mext coords
    const float elM = __expf(sL[tM]);
    __syncthreads();     // all alias reads done before any sMt16 write

    // ---- G = C @ B^T via MFMA; decay epilogue -> sMt16 (bf16) ----
    {
        const int t_row = wid * 16 + fr;
        s16x8 cfrag[2];
        #pragma unroll
        for (int ks = 0; ks < 2; ++ks)
            cfrag[ks] = *(const s16x8*)(xc + (size_t)t_row*CONV_DIM + D_INNER + D_STATE
                                        + ks*32 + fq*8);

        #pragma unroll
        for (int sf = 0; sf < 4; ++sf) {
            const int s_row = sf * 16 + fr;
            f32x4 g = (f32x4){0.f, 0.f, 0.f, 0.f};
            #pragma unroll
            for (int ks = 0; ks < 2; ++ks) {
                s16x8 bfrag = *(const s16x8*)(xc + (size_t)s_row*CONV_DIM + D_INNER
                                              + ks*32 + fq*8);
                g = __builtin_amdgcn_mfma_f32_16x16x32_bf16(cfrag[ks], bfrag, g, 0, 0, 0);
            }
            const float Ls  = pre_L[sf];
            const float dts = pre_dt[sf];
            u16 o[4];
            #pragma unroll
            for (int r = 0; r < 4; ++r) {
                const int t = wid * 16 + fq * 4 + r;
                const float e = __expf(fminf(Lt[r] - Ls, 0.f)) * dts;
                o[r] = f2bf((s_row <= t) ? g[r] * e : 0.f);
            }
            const int bo2 = s_row * 128 + ((wid * 32 + fq * 8) ^ ((s_row & 7) << 4));
            *(uint2*)((char*)sMt16 + bo2) = *(const uint2*)o;
        }
    }

    // ---- Mext rows: sMt16[64+n][t] = exp(L_t) * C_t[n] ----
    {
        uint4 c0 = *(const uint4*)(xc + (size_t)tM*CONV_DIM + D_INNER + D_STATE + nbM*16);
        uint4 c1 = *(const uint4*)(xc + (size_t)tM*CONV_DIM + D_INNER + D_STATE + nbM*16 + 8);
        const u16* pc0 = (const u16*)&c0; const u16* pc1 = (const u16*)&c1;
        #pragma unroll
        for (int j = 0; j < 16; ++j) {
            const int n = nbM * 16 + j;
            const float v = elM * bf2f(j < 8 ? pc0[j] : pc1[j - 8]);
            const int bo2 = (CHUNK + n) * 128 + ((tM * 2) ^ ((n & 7) << 4));
            *(u16*)((char*)sMt16 + bo2) = f2bf(v);
        }
    }
    __syncthreads();

    // ---- Stage B: thread (tt, pp) -> 4t x 8p ----
    const int tt = tid >> 4, pp = tid & 15;
    const int p0 = pp * 8;
    float acc[4][8];
    #pragma unroll
    for (int i = 0; i < 4; ++i)
        #pragma unroll
        for (int j = 0; j < 8; ++j) acc[i][j] = 0.f;

    const int smax = tt * 4 + 4;      // causal bound; always a multiple of 4
    for (int sb = 0; sb < smax; sb += 4) {
        #pragma unroll
        for (int si = 0; si < 4; ++si) {
            const int s = sb + si;
            const int bo = s * 128 + ((tt * 8) ^ ((s & 7) << 4));
            uint2 mv = *(const uint2*)((const char*)sMt16 + bo);
            const u16* mp = (const u16*)&mv;
            const float m0f = bf2f(mp[0]), m1f = bf2f(mp[1]);
            const float m2f = bf2f(mp[2]), m3f = bf2f(mp[3]);
            uint4 xv = *(const uint4*)&sX[s * HEADDIM + p0];
            const u16* xp = (const u16*)&xv;
            #pragma unroll
            for (int j = 0; j < 8; ++j) {
                const float xf = bf2f(xp[j]);
                acc[0][j] += m0f * xf;
                acc[1][j] += m1f * xf;
                acc[2][j] += m2f * xf;
                acc[3][j] += m3f * xf;
            }
        }
    }
    const u16* Sinit = Sbuf + ((size_t)bh*NCHUNK + k)*(D_STATE*HEADDIM);
    #pragma unroll 8
    for (int n = 0; n < D_STATE; ++n) {
        const int bo = (CHUNK + n) * 128 + ((tt * 8) ^ ((n & 7) << 4));
        uint2 mv = *(const uint2*)((const char*)sMt16 + bo);
        const u16* mp = (const u16*)&mv;
        const float m0f = bf2f(mp[0]), m1f = bf2f(mp[1]);
        const float m2f = bf2f(mp[2]), m3f = bf2f(mp[3]);
        uint4 sv = *(const uint4*)(Sinit + (size_t)n * HEADDIM + p0);
        const u16* sp = (const u16*)&sv;
        #pragma unroll
        for (int j = 0; j < 8; ++j) {
            const float sf = bf2f(sp[j]);
            acc[0][j] += m0f * sf;
            acc[1][j] += m1f * sf;
            acc[2][j] += m2f * sf;
            acc[3][j] += m3f * sf;
        }
    }
    #pragma unroll
    for (int i = 0; i < 4; ++i) {
        const int t = tt * 4 + i;
        uint4 xv = *(const uint4*)&sX[t * HEADDIM + p0];
        const u16* xp = (const u16*)&xv;
        u16 o[8];
        #pragma unroll
        for (int j = 0; j < 8; ++j)
            o[j] = f2bf(acc[i][j] + Dp * bf2f(xp[j]));
        *(uint4*)(y + ((size_t)(b*SEQLEN + t0 + t))*D_INNER + h*HEADDIM + p0)
            = *(const uint4*)o;
    }
}

// ---------------------------------------------------------------------------
// yg = y * silu(z); RMSNorm over D_INNER; bf16 in, bf16 out
// ---------------------------------------------------------------------------
__global__ __launch_bounds__(256) void gate_rmsnorm(const u16* __restrict__ z,
                                                    const u16* __restrict__ y,
                                                    const float* __restrict__ norm_w,
                                                    u16* __restrict__ yn)
{
    const int row = blockIdx.x;
    const int tid = threadIdx.x;
    const u16* zr = z + (size_t)row * D_INNER + tid * 8;
    const u16* yr = y + (size_t)row * D_INNER + tid * 8;
    u16*       o  = yn + (size_t)row * D_INNER + tid * 8;

    uint4 zv4 = *(const uint4*)zr;
    uint4 yv4 = *(const uint4*)yr;
    const u16* zp = (const u16*)&zv4;
    const u16* yp = (const u16*)&yv4;

    float vals[8];
    float ss = 0.f;
    #pragma unroll
    for (int j = 0; j < 8; ++j) {
        float zv = bf2f(zp[j]);
        float g  = bf2f(yp[j]) * (zv / (1.f + expf(-zv)));
        vals[j] = g;
        ss += g * g;
    }
    #pragma unroll
    for (int off = 32; off > 0; off >>= 1) ss += __shfl_down(ss, off);
    __shared__ float red[4];
    __shared__ float sscale;
    int wid = tid >> 6, lane = tid & 63;
    if (lane == 0) red[wid] = ss;
    __syncthreads();
    if (tid == 0)
        sscale = rsqrtf((red[0]+red[1]+red[2]+red[3]) / (float)D_INNER + 1e-5f);
    __syncthreads();
    float rms = sscale;
    const float4* nw = (const float4*)(norm_w + tid * 8);
    float4 w0 = nw[0], w1 = nw[1];
    float wv[8] = {w0.x,w0.y,w0.z,w0.w,w1.x,w1.y,w1.z,w1.w};
    u16 ov[8];
    #pragma unroll
    for (int j = 0; j < 8; ++j) ov[j] = f2bf(vals[j] * rms * wv[j]);
    *(uint4*)o = *(const uint4*)ov;
}

// ---------------------------------------------------------------------------
extern "C" void kernel_launch(void* const* d_in, const int* in_sizes, int n_in,
                              void* d_out, int out_size, void* d_ws, size_t ws_size,
                              hipStream_t stream)
{
    const float* u          = (const float*)d_in[0];
    const float* in_proj_w  = (const float*)d_in[1];
    const float* conv_w     = (const float*)d_in[2];
    const float* conv_b     = (const float*)d_in[3];
    const float* dt_bias    = (const float*)d_in[4];
    const float* A_log      = (const float*)d_in[5];
    const float* D_param    = (const float*)d_in[6];
    const float* norm_w     = (const float*)d_in[7];
    const float* out_proj_w = (const float*)d_in[8];
    float* out = (float*)d_out;

    char* w = (char*)d_ws;
    u16* z_bf     = (u16*)w;  w += (size_t)NROWS * D_INNER  * 2;   // 16.78 MB
    u16* xBC_bf   = (u16*)w;  w += (size_t)NROWS * CONV_DIM * 2;   // 17.83 MB
    u16* xconv_bf = (u16*)w;  w += (size_t)NROWS * CONV_DIM * 2;   // 17.83 MB
    u16* yb_bf    = (u16*)w;  w += (size_t)NROWS * D_INNER  * 2;   // 16.78 MB
    u16* dtraw_bf = (u16*)w;  w += (size_t)NROWS * NHEADS   * 2;   // 0.13 MB
    float* dtw    = (float*)w; w += (size_t)NROWS * NHEADS  * 4;   // 0.26 MB
    float* Tbuf   = (float*)w; w += (size_t)BATCH*NHEADS*NCHUNK * 4;
    u16* Sbuf     = (u16*)w;  w += (size_t)BATCH*NHEADS*NCHUNK*D_STATE*HEADDIM * 2; // 16.78 MB
    u16* u_bf     = (u16*)w;  w += (size_t)NROWS * D_MODEL  * 2;   // 8.39 MB
    u16* w_in_bf  = (u16*)w;  w += (size_t)NPAD  * D_MODEL  * 2;   // 8.91 MB
    u16* w_out_bf = (u16*)w;  w += (size_t)D_MODEL * D_INNER * 2;  // 4.19 MB
    u16* yn_bf    = xconv_bf;   // xconv dead after chunk_output

    // 0) all f32 -> bf16 conversions in one dispatch
    cvt_all<<<(CVT_N0+CVT_N1+CVT_N2 + 255)/256, 256, 0, stream>>>(
        u, in_proj_w, out_proj_w, u_bf, w_in_bf, w_out_bf);

    // 1) in_proj GEMM (8-wave 512-thr); grid 34 x 32 = 1088 (rect mapping)
    dim3 g1(NPAD/128, NROWS/128);
    gemm_in512<<<g1, 512, 0, stream>>>(u_bf, w_in_bf, D_MODEL,
                                       z_bf, D_INNER, D_INNER,
                                       xBC_bf, D_INNER + CONV_DIM, CONV_DIM,
                                       dtraw_bf, D_IN_PROJ, NHEADS);

    // 2) conv + SiLU + dt softplus (merged)
    int ntot = NCONV8 + NROWS * NHEADS;
    conv_silu_dt<<<(ntot + 255) / 256, 256, 0, stream>>>(
        xBC_bf, conv_w, conv_b, xconv_bf, dtraw_bf, dt_bias, dtw);

    // 3) chunked scan
    chunk_state<<<BATCH*NHEADS*NCHUNK, 256, 0, stream>>>(xconv_bf, dtw, A_log, Sbuf, Tbuf);
    chunk_seq_par<<<BATCH*NHEADS*8, 256, 0, stream>>>(Sbuf, Tbuf);
    chunk_output<<<BATCH*NHEADS*NCHUNK, 256, 0, stream>>>(xconv_bf, dtw, A_log, D_param,
                                                          Sbuf, yb_bf);

    // 4) gate + RMSNorm -> bf16
    gate_rmsnorm<<<NROWS, 256, 0, stream>>>(z_bf, yb_bf, norm_w, yn_bf);

    // 5) out_proj GEMM (8-wave 512-thr, LDS-staged f32 epilogue)
    dim3 g6(D_MODEL/128, NROWS/128);
    gemm_out512<<<g6, 512, 0, stream>>>(yn_bf, w_out_bf, D_INNER, out, D_MODEL);
}

// Round 22
// 181.942 us; speedup vs baseline: 1.1274x; 1.1152x over previous
//
#include <hip/hip_runtime.h>
#include <cstdint>
#include <cstddef>

#define D_MODEL   1024
#define D_STATE   64
#define D_CONV    4
#define HEADDIM   128
#define NHEADS    16
#define D_INNER   2048
#define CONV_DIM  2176          // D_INNER + 2*D_STATE
#define D_IN_PROJ 4240          // 2*D_INNER + 2*D_STATE + NHEADS
#define NPAD      4352          // D_IN_PROJ padded to multiple of 128
#define BATCH     2
#define SEQLEN    2048
#define NROWS     (BATCH*SEQLEN)   // 4096
#define CHUNK     64
#define NCHUNK    (SEQLEN/CHUNK)   // 32

using u16   = unsigned short;
using s16x8 = __attribute__((ext_vector_type(8))) short;   // 8 bf16 (4 VGPRs)
using f32x4 = __attribute__((ext_vector_type(4))) float;   // MFMA accumulator

// ---------------------------------------------------------------------------
// helpers
// ---------------------------------------------------------------------------
__device__ __forceinline__ u16 f2bf(float f) {
    union { float f; unsigned u; } v; v.f = f;
    unsigned r = v.u + 0x7fffu + ((v.u >> 16) & 1u);   // round-to-nearest-even
    return (u16)(r >> 16);
}
__device__ __forceinline__ float bf2f(u16 x) {
    union { unsigned u; float f; } v; v.u = ((unsigned)x) << 16;
    return v.f;
}

__device__ __forceinline__ void gload16(const u16* g, u16* l) {
    __builtin_amdgcn_global_load_lds(
        (const __attribute__((address_space(1))) unsigned int*)g,
        (__attribute__((address_space(3))) unsigned int*)l, 16, 0, 0);
}

__device__ __forceinline__ void cp8(const float* in, u16* out, int i) {
    const float4* p = (const float4*)(in + (size_t)i * 8);
    float4 a = p[0], b = p[1];
    u16 o[8] = {f2bf(a.x), f2bf(a.y), f2bf(a.z), f2bf(a.w),
                f2bf(b.x), f2bf(b.y), f2bf(b.z), f2bf(b.w)};
    *(uint4*)(out + (size_t)i * 8) = *(const uint4*)o;
}

// ---------------------------------------------------------------------------
// merged f32 -> bf16 conversion: u | in_proj_w (row-padded) | out_proj_w
// ---------------------------------------------------------------------------
#define CVT_N0 (NROWS*D_MODEL/8)      // 524288
#define CVT_N1 (NPAD*128)             // 557056
#define CVT_N2 (D_MODEL*D_INNER/8)    // 262144
__global__ __launch_bounds__(256) void cvt_all(
    const float* __restrict__ u, const float* __restrict__ w_in,
    const float* __restrict__ w_out,
    u16* __restrict__ u_bf, u16* __restrict__ w_in_bf, u16* __restrict__ w_out_bf)
{
    int i = blockIdx.x * 256 + threadIdx.x;
    if (i < CVT_N0) {
        cp8(u, u_bf, i);
    } else if (i < CVT_N0 + CVT_N1) {
        int j = i - CVT_N0;
        int row = j >> 7, seg = j & 127;
        u16 o[8] = {0,0,0,0,0,0,0,0};
        if (row < D_IN_PROJ) {
            const float4* p = (const float4*)(w_in + (size_t)row * D_MODEL + seg * 8);
            float4 a = p[0], b = p[1];
            o[0]=f2bf(a.x); o[1]=f2bf(a.y); o[2]=f2bf(a.z); o[3]=f2bf(a.w);
            o[4]=f2bf(b.x); o[5]=f2bf(b.y); o[6]=f2bf(b.z); o[7]=f2bf(b.w);
        }
        *(uint4*)(w_in_bf + (size_t)j * 8) = *(const uint4*)o;
    } else if (i < CVT_N0 + CVT_N1 + CVT_N2) {
        cp8(w_out, w_out_bf, i - CVT_N0 - CVT_N1);
    }
}

// ---------------------------------------------------------------------------
// in_proj GEMM: 128x128 tile, BK=64, 8 waves (512 thr), counted vmcnt(4),
// T2 swizzle, rect per-XCD mapping, LDS-staged coalesced epilogue.
// ---------------------------------------------------------------------------
#define CPITCH 136    // u16 pitch for epilogue tile (272B rows, 16B aligned)
__global__ __launch_bounds__(512) void gemm_in512(
    const u16* __restrict__ A, const u16* __restrict__ B, int K,
    u16* __restrict__ C0, int n1, int ld0,
    u16* __restrict__ C1, int n2, int ld1,
    u16* __restrict__ C2, int n3, int ld2)
{
    __shared__ u16 smem[4 * 128 * 64];          // 64 KB arena

    const int tid  = threadIdx.x;
    const int wid  = tid >> 6;               // 0..7
    const int lane = tid & 63;
    const int wm   = wid >> 2, wn = wid & 3; // 2 x 4 wave grid

    // rectangular XCD mapping: grid 34x32 = 1088 = 8 XCD x (8m x 17n)
    const int gx   = gridDim.x;                  // 34
    int orig = blockIdx.y * gx + blockIdx.x;     // 0..1087
    const int xcd = orig & 7;
    const int loc = orig >> 3;                   // 0..135
    const int mt  = (xcd >> 1) * 8  + (loc & 7); // 0..31
    const int nt  = (xcd & 1) * 17 + (loc >> 3); // 0..33
    const int m0 = mt * 128, n0 = nt * 128;

    const int lrow = lane >> 3;
    const int lseg = (lane & 7) ^ lrow;
    const u16* gA = A + (size_t)(m0 + lrow) * K + lseg * 8;
    const u16* gB = B + (size_t)(n0 + lrow) * K + lseg * 8;

    f32x4 acc[4][2];
    #pragma unroll
    for (int i = 0; i < 4; ++i)
        #pragma unroll
        for (int j = 0; j < 2; ++j)
            acc[i][j] = (f32x4){0.f, 0.f, 0.f, 0.f};

    const int fr = lane & 15, fq = lane >> 4;
    const int nstep = K >> 6;

    auto stage = [&](int buf, int k0) {
        u16* sAp = smem + buf * 8192;
        u16* sBp = smem + 16384 + buf * 8192;
        #pragma unroll
        for (int i = 0; i < 2; ++i) {
            const int r0 = (i * 8 + wid) * 8;
            gload16(gA + (size_t)r0 * K + k0, sAp + r0 * 64);
            gload16(gB + (size_t)r0 * K + k0, sBp + r0 * 64);
        }
    };

    stage(0, 0);
    int cur = 0;
    for (int step = 0; step < nstep; ++step) {
        if (step + 1 < nstep) {
            stage(cur ^ 1, (step + 1) * 64);
            asm volatile("s_waitcnt vmcnt(4)" ::: "memory");
        } else {
            asm volatile("s_waitcnt vmcnt(0)" ::: "memory");
        }
        __builtin_amdgcn_s_barrier();
        __builtin_amdgcn_sched_barrier(0);

        const u16* sAc = smem + cur * 8192;
        const u16* sBc = smem + 16384 + cur * 8192;
        #pragma unroll
        for (int ks = 0; ks < 2; ++ks) {
            s16x8 bfr[2];
            #pragma unroll
            for (int ni = 0; ni < 2; ++ni) {
                const int row = wn * 32 + ni * 16 + fr;
                const int bo = row * 128 + ((ks * 64 + fq * 16) ^ ((row & 7) << 4));
                bfr[ni] = *(const s16x8*)((const char*)sBc + bo);
            }
            #pragma unroll
            for (int mi = 0; mi < 4; ++mi) {
                const int row = wm * 64 + mi * 16 + fr;
                const int bo = row * 128 + ((ks * 64 + fq * 16) ^ ((row & 7) << 4));
                s16x8 af = *(const s16x8*)((const char*)sAc + bo);
                #pragma unroll
                for (int ni = 0; ni < 2; ++ni)
                    acc[mi][ni] = __builtin_amdgcn_mfma_f32_16x16x32_bf16(
                        af, bfr[ni], acc[mi][ni], 0, 0, 0);
            }
        }

        __builtin_amdgcn_sched_barrier(0);
        __builtin_amdgcn_s_barrier();
        cur ^= 1;
    }
    __builtin_amdgcn_sched_barrier(0);   // keep epilogue ds_writes after loop

    // ---- LDS-staged epilogue: frag layout -> row-linear -> 16B stores ----
    u16* sC = smem;                       // K-loop buffers dead now
    #pragma unroll
    for (int mi = 0; mi < 4; ++mi) {
        #pragma unroll
        for (int j = 0; j < 4; ++j) {
            const int rl = wm * 64 + mi * 16 + fq * 4 + j;
            #pragma unroll
            for (int ni = 0; ni < 2; ++ni) {
                const int cl = wn * 32 + ni * 16 + fr;
                sC[rl * CPITCH + cl] = f2bf(acc[mi][ni][j]);
            }
        }
    }
    __syncthreads();
    #pragma unroll
    for (int k2 = 0; k2 < 4; ++k2) {
        const int g  = tid + k2 * 512;        // 0..2047
        const int rl = g >> 4, cg = g & 15;
        uint4 v = *(const uint4*)&sC[rl * CPITCH + cg * 8];
        const int r = m0 + rl, c = n0 + cg * 8;
        if (c < n1)      *(uint4*)(C0 + (size_t)r * ld0 + c)        = v;
        else if (c < n2) *(uint4*)(C1 + (size_t)r * ld1 + (c - n1)) = v;
        else if (c < n3) *(uint4*)(C2 + (size_t)r * ld2 + (c - n2)) = v;
    }
}

// ---------------------------------------------------------------------------
// out_proj GEMM: 128x128 tile, BK=64, 8 waves (512 thr), counted vmcnt(4),
// LDS-staged f32 epilogue in two 64-row halves (coalesced 16B stores).
// ---------------------------------------------------------------------------
__global__ __launch_bounds__(512) void gemm_out512(
    const u16* __restrict__ A, const u16* __restrict__ B, int K,
    float* __restrict__ C, int N)
{
    __shared__ u16 smem[4 * 128 * 64];          // 64 KB arena

    const int tid  = threadIdx.x;
    const int wid  = tid >> 6;               // 0..7
    const int lane = tid & 63;
    const int wm   = wid >> 2, wn = wid & 3; // 2 x 4 wave grid

    const int gx   = gridDim.x;
    const int nwg  = gx * gridDim.y;
    const int cpx  = nwg >> 3;
    int orig = blockIdx.y * gx + blockIdx.x;
    int wg   = (orig & 7) * cpx + (orig >> 3);
    const int m0 = (wg / gx) * 128, n0 = (wg % gx) * 128;

    const int lrow = lane >> 3;
    const int lseg = (lane & 7) ^ lrow;
    const u16* gA = A + (size_t)(m0 + lrow) * K + lseg * 8;
    const u16* gB = B + (size_t)(n0 + lrow) * K + lseg * 8;

    f32x4 acc[4][2];
    #pragma unroll
    for (int i = 0; i < 4; ++i)
        #pragma unroll
        for (int j = 0; j < 2; ++j)
            acc[i][j] = (f32x4){0.f, 0.f, 0.f, 0.f};

    const int fr = lane & 15, fq = lane >> 4;
    const int nstep = K >> 6;

    auto stage = [&](int buf, int k0) {
        u16* sAp = smem + buf * 8192;
        u16* sBp = smem + 16384 + buf * 8192;
        #pragma unroll
        for (int i = 0; i < 2; ++i) {
            const int r0 = (i * 8 + wid) * 8;
            gload16(gA + (size_t)r0 * K + k0, sAp + r0 * 64);
            gload16(gB + (size_t)r0 * K + k0, sBp + r0 * 64);
        }
    };

    stage(0, 0);
    int cur = 0;
    for (int step = 0; step < nstep; ++step) {
        if (step + 1 < nstep) {
            stage(cur ^ 1, (step + 1) * 64);
            asm volatile("s_waitcnt vmcnt(4)" ::: "memory");
        } else {
            asm volatile("s_waitcnt vmcnt(0)" ::: "memory");
        }
        __builtin_amdgcn_s_barrier();
        __builtin_amdgcn_sched_barrier(0);

        const u16* sAc = smem + cur * 8192;
        const u16* sBc = smem + 16384 + cur * 8192;
        #pragma unroll
        for (int ks = 0; ks < 2; ++ks) {
            s16x8 bfr[2];
            #pragma unroll
            for (int ni = 0; ni < 2; ++ni) {
                const int row = wn * 32 + ni * 16 + fr;
                const int bo = row * 128 + ((ks * 64 + fq * 16) ^ ((row & 7) << 4));
                bfr[ni] = *(const s16x8*)((const char*)sBc + bo);
            }
            #pragma unroll
            for (int mi = 0; mi < 4; ++mi) {
                const int row = wm * 64 + mi * 16 + fr;
                const int bo = row * 128 + ((ks * 64 + fq * 16) ^ ((row & 7) << 4));
                s16x8 af = *(const s16x8*)((const char*)sAc + bo);
                #pragma unroll
                for (int ni = 0; ni < 2; ++ni)
                    acc[mi][ni] = __builtin_amdgcn_mfma_f32_16x16x32_bf16(
                        af, bfr[ni], acc[mi][ni], 0, 0, 0);
            }
        }

        __builtin_amdgcn_sched_barrier(0);
        __builtin_amdgcn_s_barrier();
        cur ^= 1;
    }
    __builtin_amdgcn_sched_barrier(0);

    // ---- LDS-staged f32 epilogue, two 64-row halves (pitch 132 f32) ----
    float* sCf = (float*)smem;            // 64x132x4 = 33.8 KB per half
    #pragma unroll
    for (int h2 = 0; h2 < 2; ++h2) {
        if (wm == h2) {
            #pragma unroll
            for (int mi = 0; mi < 4; ++mi)
                #pragma unroll
                for (int j = 0; j < 4; ++j) {
                    const int rl = mi * 16 + fq * 4 + j;        // 0..63
                    #pragma unroll
                    for (int ni = 0; ni < 2; ++ni) {
                        const int cl = wn * 32 + ni * 16 + fr;
                        sCf[rl * 132 + cl] = acc[mi][ni][j];
                    }
                }
        }
        __syncthreads();
        #pragma unroll
        for (int k2 = 0; k2 < 4; ++k2) {
            const int g  = tid + k2 * 512;    // 0..2047
            const int rl = g >> 5, cg = g & 31;
            float4 v = *(const float4*)&sCf[rl * 132 + cg * 4];
            *(float4*)(C + (size_t)(m0 + h2 * 64 + rl) * N + n0 + cg * 4) = v;
        }
        __syncthreads();
    }
}

// ---------------------------------------------------------------------------
// Depthwise causal conv(4)+bias+SiLU (8 ch/thread) and, in tail blocks,
// dt = softplus(dtraw + dt_bias)  (merged to save a dispatch).
// ---------------------------------------------------------------------------
#define NCONV8 (NROWS*(CONV_DIM/8))
__global__ __launch_bounds__(256) void conv_silu_dt(
    const u16* __restrict__ xBC, const float* __restrict__ conv_w,
    const float* __restrict__ conv_b, u16* __restrict__ xconv,
    const u16* __restrict__ dtraw, const float* __restrict__ dt_bias,
    float* __restrict__ dtw)
{
    int idx = blockIdx.x * 256 + threadIdx.x;
    if (idx < NCONV8) {
        int c8  = idx % (CONV_DIM / 8);
        int row = idx / (CONV_DIM / 8);     // b*SEQLEN + l
        int l   = row % SEQLEN;
        int b   = row / SEQLEN;
        int c0  = c8 * 8;
        const u16* src = xBC + (size_t)(b * SEQLEN) * CONV_DIM + c0;

        uint4 z4 = {0u, 0u, 0u, 0u};
        uint4 v3 = *(const uint4*)(src + (size_t)l * CONV_DIM);
        uint4 v2 = (l >= 1) ? *(const uint4*)(src + (size_t)(l-1) * CONV_DIM) : z4;
        uint4 v1 = (l >= 2) ? *(const uint4*)(src + (size_t)(l-2) * CONV_DIM) : z4;
        uint4 v0 = (l >= 3) ? *(const uint4*)(src + (size_t)(l-3) * CONV_DIM) : z4;
        const u16* p0 = (const u16*)&v0; const u16* p1 = (const u16*)&v1;
        const u16* p2 = (const u16*)&v2; const u16* p3 = (const u16*)&v3;

        u16 o[8];
        #pragma unroll
        for (int j = 0; j < 8; ++j) {
            const float4 w4 = *(const float4*)(conv_w + (size_t)(c0 + j) * 4);
            float acc = conv_b[c0 + j]
                      + bf2f(p0[j]) * w4.x + bf2f(p1[j]) * w4.y
                      + bf2f(p2[j]) * w4.z + bf2f(p3[j]) * w4.w;
            o[j] = f2bf(acc / (1.f + expf(-acc)));   // SiLU
        }
        *(uint4*)(xconv + (size_t)row * CONV_DIM + c0) = *(const uint4*)o;
    } else {
        int k = idx - NCONV8;
        if (k < NROWS * NHEADS) {
            int h = k & (NHEADS - 1);
            float v = bf2f(dtraw[k]) + dt_bias[h];
            dtw[k] = (v > 20.f) ? v : log1pf(expf(v));
        }
    }
}

// ---------------------------------------------------------------------------
// Phase A: chunk state.  S[n][p] = sum_s (W_s*B_s[n]) * x_s[p]  (bf16 out)
// sWB bf16 (8 KB).  Inner loop unrolled 4x for LDS-load batching.
// ---------------------------------------------------------------------------
__global__ __launch_bounds__(256) void chunk_state(
    const u16* __restrict__ xconv, const float* __restrict__ dtw,
    const float* __restrict__ A_log, u16* __restrict__ Sbuf,
    float* __restrict__ Tbuf)
{
    const int blk = blockIdx.x;
    const int k  = blk & (NCHUNK-1);
    const int bh = blk >> 5;
    const int b  = bh >> 4, h = bh & 15;
    const int tid = threadIdx.x;
    const int wid = tid >> 6, lane = tid & 63;
    const float A = -expf(A_log[h]);

    __shared__ float sdt[CHUNK], sW[CHUNK], sT;
    __shared__ u16   sWB16[CHUNK * D_STATE];   // bf16, 128B rows, swz 16B units
    __shared__ u16   sX[CHUNK * HEADDIM];      // linear (DMA-staged)

    const int t0 = k * CHUNK;
    const u16* xc = xconv + (size_t)(b*SEQLEN + t0) * CONV_DIM;

    if (tid < CHUNK)
        sdt[tid] = dtw[(size_t)(b*SEQLEN + t0 + tid)*NHEADS + h];
    __syncthreads();
    if (tid < CHUNK) {
        float a = 0.f, pref = 0.f;
        for (int r = 0; r < CHUNK; ++r) {
            a += sdt[r] * A;
            if (r == tid) pref = a;
        }
        sW[tid] = __expf(a - pref) * sdt[tid];   // exp(T - L_s) * dt_s
        if (tid == 0) sT = a;
    }
    __syncthreads();

    // stage x via DMA: 4 calls/wave, 4 rows per call
    #pragma unroll
    for (int c = 0; c < 4; ++c) {
        const int r = wid * 16 + c * 4 + (lane >> 4);
        const int seg = lane & 15;
        gload16(xc + (size_t)r * CONV_DIM + h * HEADDIM + seg * 8,
                sX + (wid * 16 + c * 4) * HEADDIM);
    }
    // stage W*B (bf16, 128B rows, 16B-unit XOR swizzle)
    {
        const int s = tid >> 2, nb = tid & 3;
        const float wv = sW[s];
        uint4 b0 = *(const uint4*)(xc + (size_t)s*CONV_DIM + D_INNER + nb*16);
        uint4 b1 = *(const uint4*)(xc + (size_t)s*CONV_DIM + D_INNER + nb*16 + 8);
        const u16* pb0 = (const u16*)&b0; const u16* pb1 = (const u16*)&b1;
        u16 o[16];
        #pragma unroll
        for (int j = 0; j < 8; ++j) {
            o[j]     = f2bf(wv * bf2f(pb0[j]));
            o[8 + j] = f2bf(wv * bf2f(pb1[j]));
        }
        #pragma unroll
        for (int u2 = 0; u2 < 2; ++u2) {
            const int bo = s * 128 + ((nb * 32 + u2 * 16) ^ ((s & 7) << 4));
            *(uint4*)((char*)sWB16 + bo) = *(const uint4*)&o[u2 * 8];
        }
    }
    __syncthreads();

    // compute: thread (nn, pp) -> 4n x 8p
    const int nn = tid >> 4, pp = tid & 15;
    const int p0 = pp * 8, n0 = nn * 4;
    const int base16 = (nn >> 1) << 4;       // 16B granule of this nn's 8B read
    const int sub8   = (nn & 1) * 8;
    float acc[4][8];
    #pragma unroll
    for (int i = 0; i < 4; ++i)
        #pragma unroll
        for (int j = 0; j < 8; ++j) acc[i][j] = 0.f;

    for (int sb = 0; sb < CHUNK; sb += 4) {
        #pragma unroll
        for (int si = 0; si < 4; ++si) {
            const int s = sb + si;
            const int bo = s * 128 + ((base16 ^ ((s & 7) << 4)) + sub8);
            uint2 wv2 = *(const uint2*)((const char*)sWB16 + bo);
            const u16* wp = (const u16*)&wv2;
            const float w0f = bf2f(wp[0]), w1f = bf2f(wp[1]);
            const float w2f = bf2f(wp[2]), w3f = bf2f(wp[3]);
            uint4 xv = *(const uint4*)&sX[s * HEADDIM + p0];
            const u16* xp = (const u16*)&xv;
            #pragma unroll
            for (int j = 0; j < 8; ++j) {
                const float xf = bf2f(xp[j]);
                acc[0][j] += w0f * xf;
                acc[1][j] += w1f * xf;
                acc[2][j] += w2f * xf;
                acc[3][j] += w3f * xf;
            }
        }
    }
    u16* So = Sbuf + ((size_t)bh*NCHUNK + k)*(D_STATE*HEADDIM);
    #pragma unroll
    for (int i = 0; i < 4; ++i) {
        u16 o[8];
        #pragma unroll
        for (int j = 0; j < 8; ++j) o[j] = f2bf(acc[i][j]);
        *(uint4*)(So + (size_t)(n0 + i) * HEADDIM + p0) = *(const uint4*)o;
    }
    if (tid == 0) Tbuf[bh*NCHUNK + k] = sT;
}

// ---------------------------------------------------------------------------
// Inter-chunk sequential pass (bf16 S, f32 accumulation), parallel over (n,p)
// ---------------------------------------------------------------------------
__global__ __launch_bounds__(256) void chunk_seq_par(u16* __restrict__ Sbuf,
                                                     const float* __restrict__ Tbuf)
{
    const int blk = blockIdx.x;           // 32 bh * 8 = 256 blocks
    const int bh  = blk >> 3;
    const int sub = blk & 7;
    __shared__ float seT[NCHUNK];
    if (threadIdx.x < NCHUNK)
        seT[threadIdx.x] = __expf(Tbuf[bh*NCHUNK + threadIdx.x]);
    __syncthreads();

    const int idx4 = sub * 256 + threadIdx.x;    // 4-elem index in [0,2048)
    u16* base = Sbuf + (size_t)bh*NCHUNK*(D_STATE*HEADDIM) + (size_t)idx4*4;
    float run[4];
    #pragma unroll
    for (int j = 0; j < 4; ++j) run[j] = 0.f;
    for (int k = 0; k < NCHUNK; ++k) {
        u16* p = base + (size_t)k * (D_STATE*HEADDIM);
        uint2 v = *(const uint2*)p;
        const u16* pv = (const u16*)&v;
        const float eT = seT[k];
        u16 o[4];
        #pragma unroll
        for (int j = 0; j < 4; ++j) {
            float tmp = bf2f(pv[j]);
            o[j] = f2bf(run[j]);
            run[j] = run[j] * eT + tmp;
        }
        *(uint2*)p = *(const uint2*)o;
    }
}

// ---------------------------------------------------------------------------
// Phase B v2: stage B via MFMA.
// Mfull[64 t][128 k] (k = s' 0..63 = causal-masked M; 64..127 = Mext), swz.
// X and Sinit transposed in-kernel to sXT[p][s], sST[p][n] (swz) from global.
// Y = Mfull @ [X;Sinit]^T-operand form: 32 MFMA/wave.  48 KB LDS.
// ---------------------------------------------------------------------------
__global__ __launch_bounds__(256) void chunk_output(
    const u16* __restrict__ xconv, const float* __restrict__ dtw,
    const float* __restrict__ A_log, const float* __restrict__ D_param,
    const u16* __restrict__ Sbuf, u16* __restrict__ y)
{
    const int blk = blockIdx.x;
    const int k  = blk & (NCHUNK-1);
    const int bh = blk >> 5;
    const int b  = bh >> 4, h = bh & 15;
    const int tid = threadIdx.x;
    const int wid = tid >> 6, lane = tid & 63;
    const float A  = -expf(A_log[h]);
    const float Dp = D_param[h];

    __shared__ u16 arena[3 * 8192];      // 48 KB: [Mfull | sXT | sST]
    u16* Mfull = arena;                  // [64 t][128 k] bf16, 256B rows, swz
    u16* sXT   = arena + 8192;           // [128 p][64 s] bf16, 128B rows, swz
    u16* sST   = arena + 16384;          // [128 p][64 n] bf16, 128B rows, swz
    u16* eT    = arena + 8192;           // epilogue tile [64][CPITCH] (17 KB)
    float* sdt = (float*)Mfull;          // alias rows t=0,1 (512 B)
    float* sL  = sdt + CHUNK;

    const int t0 = k * CHUNK;
    const u16* xc = xconv + (size_t)(b*SEQLEN + t0) * CONV_DIM;
    const u16* Sinit = Sbuf + ((size_t)bh*NCHUNK + k)*(D_STATE*HEADDIM);

    if (tid < CHUNK)
        sdt[tid] = dtw[(size_t)(b*SEQLEN + t0 + tid)*NHEADS + h];
    __syncthreads();
    if (tid < CHUNK) {
        float a = 0.f, pref = 0.f;
        for (int r = 0; r < CHUNK; ++r) {
            a += sdt[r] * A;
            if (r == tid) pref = a;
        }
        sL[tid] = pref;
    }
    __syncthreads();

    // ---- PRELOAD from sdt/sL into registers (before Mfull overwrite) ----
    const int fr = lane & 15, fq = lane >> 4;
    float4 sL4 = *(const float4*)&sL[wid * 16 + fq * 4];
    const float Lt[4] = {sL4.x, sL4.y, sL4.z, sL4.w};
    float pre_L[4], pre_dt[4];
    #pragma unroll
    for (int sf = 0; sf < 4; ++sf) {
        const int s_row = sf * 16 + fr;
        pre_L[sf]  = sL[s_row];
        pre_dt[sf] = sdt[s_row];
    }
    const int tM = tid >> 2, nbM = tid & 3;           // Mext coords
    const float elM = __expf(sL[tM]);
    __syncthreads();     // all alias reads done before Mfull writes

    // ---- P2: transpose X and Sinit into sXT / sST (swizzled scatter) ----
    {
        const int sr = tid >> 2;          // source row 0..63
        const int pg = tid & 3;           // p-group 0..3
        #pragma unroll
        for (int i = 0; i < 4; ++i) {
            const int pb = pg * 32 + i * 8;
            uint4 xv = *(const uint4*)(xc + (size_t)sr * CONV_DIM + h * HEADDIM + pb);
            const u16* xp = (const u16*)&xv;
            uint4 sv = *(const uint4*)(Sinit + (size_t)sr * HEADDIM + pb);
            const u16* sp = (const u16*)&sv;
            const int cb = sr * 2;                       // col byte in dest row
            const int cbase = (cb & ~15), coff = (cb & 15);
            #pragma unroll
            for (int j = 0; j < 8; ++j) {
                const int p = pb + j;
                const int bo = p * 128 + (cbase ^ ((p & 7) << 4)) + coff;
                *(u16*)((char*)sXT + bo) = xp[j];
                *(u16*)((char*)sST + bo) = sp[j];
            }
        }
    }

    // ---- P3: stage A MFMA (G = C@B^T from global) -> Mfull[t][s] ----
    {
        const int t_row = wid * 16 + fr;
        s16x8 cfrag[2];
        #pragma unroll
        for (int ks = 0; ks < 2; ++ks)
            cfrag[ks] = *(const s16x8*)(xc + (size_t)t_row*CONV_DIM + D_INNER + D_STATE
                                        + ks*32 + fq*8);

        #pragma unroll
        for (int sf = 0; sf < 4; ++sf) {
            const int s_row = sf * 16 + fr;
            f32x4 g = (f32x4){0.f, 0.f, 0.f, 0.f};
            #pragma unroll
            for (int ks = 0; ks < 2; ++ks) {
                s16x8 bfrag = *(const s16x8*)(xc + (size_t)s_row*CONV_DIM + D_INNER
                                              + ks*32 + fq*8);
                g = __builtin_amdgcn_mfma_f32_16x16x32_bf16(cfrag[ks], bfrag, g, 0, 0, 0);
            }
            const float Ls  = pre_L[sf];
            const float dts = pre_dt[sf];
            const int cb = s_row * 2;
            const int cbase = (cb & ~15), coff = (cb & 15);
            #pragma unroll
            for (int r = 0; r < 4; ++r) {
                const int t = wid * 16 + fq * 4 + r;
                const float e = __expf(fminf(Lt[r] - Ls, 0.f)) * dts;
                const float val = (s_row <= t) ? g[r] * e : 0.f;
                const int bo = t * 256 + (cbase ^ ((t & 7) << 4)) + coff;
                *(u16*)((char*)Mfull + bo) = f2bf(val);
            }
        }
    }
    // ---- Mext rows: Mfull[t][64+n] = exp(L_t) * C_t[n] (uint4 writes) ----
    {
        uint4 c0 = *(const uint4*)(xc + (size_t)tM*CONV_DIM + D_INNER + D_STATE + nbM*16);
        uint4 c1 = *(const uint4*)(xc + (size_t)tM*CONV_DIM + D_INNER + D_STATE + nbM*16 + 8);
        const u16* pc0 = (const u16*)&c0; const u16* pc1 = (const u16*)&c1;
        u16 o[16];
        #pragma unroll
        for (int j = 0; j < 16; ++j)
            o[j] = f2bf(elM * bf2f(j < 8 ? pc0[j] : pc1[j - 8]));
        #pragma unroll
        for (int u2 = 0; u2 < 2; ++u2) {
            const int cb = 128 + nbM * 32 + u2 * 16;     // col byte (k=64+n)
            const int bo = tM * 256 + (cb ^ ((tM & 7) << 4));
            *(uint4*)((char*)Mfull + bo) = *(const uint4*)&o[u2 * 8];
        }
    }
    __syncthreads();

    // ---- P4: stage B MFMA: Y[t][p] = Mfull[t][k] @ XS^T[p][k] ----
    f32x4 accB[8];
    #pragma unroll
    for (int i = 0; i < 8; ++i) accB[i] = (f32x4){0.f, 0.f, 0.f, 0.f};

    #pragma unroll
    for (int ks = 0; ks < 4; ++ks) {
        const int ta = wid * 16 + fr;
        const int boA = ta * 256 + ((ks * 64 + fq * 16) ^ ((ta & 7) << 4));
        s16x8 afr = *(const s16x8*)((const char*)Mfull + boA);
        const u16* src = (ks < 2) ? sXT : sST;
        const int cbB = (ks & 1) * 64 + fq * 16;
        #pragma unroll
        for (int pt = 0; pt < 8; ++pt) {
            const int p = pt * 16 + fr;
            const int boB = p * 128 + (cbB ^ ((p & 7) << 4));
            s16x8 bfrB = *(const s16x8*)((const char*)src + boB);
            accB[pt] = __builtin_amdgcn_mfma_f32_16x16x32_bf16(afr, bfrB, accB[pt], 0, 0, 0);
        }
    }

    // ---- D*x in fragment layout (reads sXT scalar) ----
    #pragma unroll
    for (int pt = 0; pt < 8; ++pt) {
        const int p = pt * 16 + fr;
        #pragma unroll
        for (int r = 0; r < 4; ++r) {
            const int t = wid * 16 + fq * 4 + r;
            const int cb = t * 2;
            const int bo = p * 128 + ((cb & ~15) ^ ((p & 7) << 4)) + (cb & 15);
            accB[pt][r] += Dp * bf2f(*(const u16*)((const char*)sXT + bo));
        }
    }
    __syncthreads();     // all sXT/sST reads done before eT overwrite

    // ---- epilogue: frag -> eT row-linear -> coalesced stores ----
    #pragma unroll
    for (int pt = 0; pt < 8; ++pt) {
        #pragma unroll
        for (int r = 0; r < 4; ++r) {
            const int t = wid * 16 + fq * 4 + r;
            eT[t * CPITCH + pt * 16 + fr] = f2bf(accB[pt][r]);
        }
    }
    __syncthreads();
    #pragma unroll
    for (int k2 = 0; k2 < 4; ++k2) {
        const int g  = tid + k2 * 256;        // 0..1023 = 64 rows x 16 groups
        const int rl = g >> 4, cg = g & 15;
        uint4 v = *(const uint4*)&eT[rl * CPITCH + cg * 8];
        *(uint4*)(y + ((size_t)(b*SEQLEN + t0 + rl))*D_INNER + h*HEADDIM + cg*8) = v;
    }
}

// ---------------------------------------------------------------------------
// yg = y * silu(z); RMSNorm over D_INNER; bf16 in, bf16 out
// ---------------------------------------------------------------------------
__global__ __launch_bounds__(256) void gate_rmsnorm(const u16* __restrict__ z,
                                                    const u16* __restrict__ y,
                                                    const float* __restrict__ norm_w,
                                                    u16* __restrict__ yn)
{
    const int row = blockIdx.x;
    const int tid = threadIdx.x;
    const u16* zr = z + (size_t)row * D_INNER + tid * 8;
    const u16* yr = y + (size_t)row * D_INNER + tid * 8;
    u16*       o  = yn + (size_t)row * D_INNER + tid * 8;

    uint4 zv4 = *(const uint4*)zr;
    uint4 yv4 = *(const uint4*)yr;
    const u16* zp = (const u16*)&zv4;
    const u16* yp = (const u16*)&yv4;

    float vals[8];
    float ss = 0.f;
    #pragma unroll
    for (int j = 0; j < 8; ++j) {
        float zv = bf2f(zp[j]);
        float g  = bf2f(yp[j]) * (zv / (1.f + expf(-zv)));
        vals[j] = g;
        ss += g * g;
    }
    #pragma unroll
    for (int off = 32; off > 0; off >>= 1) ss += __shfl_down(ss, off);
    __shared__ float red[4];
    __shared__ float sscale;
    int wid = tid >> 6, lane = tid & 63;
    if (lane == 0) red[wid] = ss;
    __syncthreads();
    if (tid == 0)
        sscale = rsqrtf((red[0]+red[1]+red[2]+red[3]) / (float)D_INNER + 1e-5f);
    __syncthreads();
    float rms = sscale;
    const float4* nw = (const float4*)(norm_w + tid * 8);
    float4 w0 = nw[0], w1 = nw[1];
    float wv[8] = {w0.x,w0.y,w0.z,w0.w,w1.x,w1.y,w1.z,w1.w};
    u16 ov[8];
    #pragma unroll
    for (int j = 0; j < 8; ++j) ov[j] = f2bf(vals[j] * rms * wv[j]);
    *(uint4*)o = *(const uint4*)ov;
}

// ---------------------------------------------------------------------------
extern "C" void kernel_launch(void* const* d_in, const int* in_sizes, int n_in,
                              void* d_out, int out_size, void* d_ws, size_t ws_size,
                              hipStream_t stream)
{
    const float* u          = (const float*)d_in[0];
    const float* in_proj_w  = (const float*)d_in[1];
    const float* conv_w     = (const float*)d_in[2];
    const float* conv_b     = (const float*)d_in[3];
    const float* dt_bias    = (const float*)d_in[4];
    const float* A_log      = (const float*)d_in[5];
    const float* D_param    = (const float*)d_in[6];
    const float* norm_w     = (const float*)d_in[7];
    const float* out_proj_w = (const float*)d_in[8];
    float* out = (float*)d_out;

    char* w = (char*)d_ws;
    u16* z_bf     = (u16*)w;  w += (size_t)NROWS * D_INNER  * 2;   // 16.78 MB
    u16* xBC_bf   = (u16*)w;  w += (size_t)NROWS * CONV_DIM * 2;   // 17.83 MB
    u16* xconv_bf = (u16*)w;  w += (size_t)NROWS * CONV_DIM * 2;   // 17.83 MB
    u16* yb_bf    = (u16*)w;  w += (size_t)NROWS * D_INNER  * 2;   // 16.78 MB
    u16* dtraw_bf = (u16*)w;  w += (size_t)NROWS * NHEADS   * 2;   // 0.13 MB
    float* dtw    = (float*)w; w += (size_t)NROWS * NHEADS  * 4;   // 0.26 MB
    float* Tbuf   = (float*)w; w += (size_t)BATCH*NHEADS*NCHUNK * 4;
    u16* Sbuf     = (u16*)w;  w += (size_t)BATCH*NHEADS*NCHUNK*D_STATE*HEADDIM * 2; // 16.78 MB
    u16* u_bf     = (u16*)w;  w += (size_t)NROWS * D_MODEL  * 2;   // 8.39 MB
    u16* w_in_bf  = (u16*)w;  w += (size_t)NPAD  * D_MODEL  * 2;   // 8.91 MB
    u16* w_out_bf = (u16*)w;  w += (size_t)D_MODEL * D_INNER * 2;  // 4.19 MB
    u16* yn_bf    = xconv_bf;   // xconv dead after chunk_output

    // 0) all f32 -> bf16 conversions in one dispatch
    cvt_all<<<(CVT_N0+CVT_N1+CVT_N2 + 255)/256, 256, 0, stream>>>(
        u, in_proj_w, out_proj_w, u_bf, w_in_bf, w_out_bf);

    // 1) in_proj GEMM (8-wave 512-thr); grid 34 x 32 = 1088 (rect mapping)
    dim3 g1(NPAD/128, NROWS/128);
    gemm_in512<<<g1, 512, 0, stream>>>(u_bf, w_in_bf, D_MODEL,
                                       z_bf, D_INNER, D_INNER,
                                       xBC_bf, D_INNER + CONV_DIM, CONV_DIM,
                                       dtraw_bf, D_IN_PROJ, NHEADS);

    // 2) conv + SiLU + dt softplus (merged)
    int ntot = NCONV8 + NROWS * NHEADS;
    conv_silu_dt<<<(ntot + 255) / 256, 256, 0, stream>>>(
        xBC_bf, conv_w, conv_b, xconv_bf, dtraw_bf, dt_bias, dtw);

    // 3) chunked scan
    chunk_state<<<BATCH*NHEADS*NCHUNK, 256, 0, stream>>>(xconv_bf, dtw, A_log, Sbuf, Tbuf);
    chunk_seq_par<<<BATCH*NHEADS*8, 256, 0, stream>>>(Sbuf, Tbuf);
    chunk_output<<<BATCH*NHEADS*NCHUNK, 256, 0, stream>>>(xconv_bf, dtw, A_log, D_param,
                                                          Sbuf, yb_bf);

    // 4) gate + RMSNorm -> bf16
    gate_rmsnorm<<<NROWS, 256, 0, stream>>>(z_bf, yb_bf, norm_w, yn_bf);

    // 5) out_proj GEMM (8-wave 512-thr, LDS-staged f32 epilogue)
    dim3 g6(D_MODEL/128, NROWS/128);
    gemm_out512<<<g6, 512, 0, stream>>>(yn_bf, w_out_bf, D_INNER, out, D_MODEL);
}

// Round 23
// 170.505 us; speedup vs baseline: 1.2030x; 1.0671x over previous
//
#include <hip/hip_runtime.h>
#include <cstdint>
#include <cstddef>

#define D_MODEL   1024
#define D_STATE   64
#define D_CONV    4
#define HEADDIM   128
#define NHEADS    16
#define D_INNER   2048
#define CONV_DIM  2176          // D_INNER + 2*D_STATE
#define D_IN_PROJ 4240          // 2*D_INNER + 2*D_STATE + NHEADS
#define NPAD      4352          // D_IN_PROJ padded to multiple of 128
#define BATCH     2
#define SEQLEN    2048
#define NROWS     (BATCH*SEQLEN)   // 4096
#define CHUNK     64
#define NCHUNK    (SEQLEN/CHUNK)   // 32

using u16   = unsigned short;
using s16x8 = __attribute__((ext_vector_type(8))) short;   // 8 bf16 (4 VGPRs)
using f32x4 = __attribute__((ext_vector_type(4))) float;   // MFMA accumulator

// ---------------------------------------------------------------------------
// helpers
// ---------------------------------------------------------------------------
__device__ __forceinline__ u16 f2bf(float f) {
    union { float f; unsigned u; } v; v.f = f;
    unsigned r = v.u + 0x7fffu + ((v.u >> 16) & 1u);   // round-to-nearest-even
    return (u16)(r >> 16);
}
__device__ __forceinline__ float bf2f(u16 x) {
    union { unsigned u; float f; } v; v.u = ((unsigned)x) << 16;
    return v.f;
}

__device__ __forceinline__ void gload16(const u16* g, u16* l) {
    __builtin_amdgcn_global_load_lds(
        (const __attribute__((address_space(1))) unsigned int*)g,
        (__attribute__((address_space(3))) unsigned int*)l, 16, 0, 0);
}

__device__ __forceinline__ void cp8(const float* in, u16* out, int i) {
    const float4* p = (const float4*)(in + (size_t)i * 8);
    float4 a = p[0], b = p[1];
    u16 o[8] = {f2bf(a.x), f2bf(a.y), f2bf(a.z), f2bf(a.w),
                f2bf(b.x), f2bf(b.y), f2bf(b.z), f2bf(b.w)};
    *(uint4*)(out + (size_t)i * 8) = *(const uint4*)o;
}

// ---------------------------------------------------------------------------
// merged f32 -> bf16 conversion: u | in_proj_w (row-padded) | out_proj_w
// ---------------------------------------------------------------------------
#define CVT_N0 (NROWS*D_MODEL/8)      // 524288
#define CVT_N1 (NPAD*128)             // 557056
#define CVT_N2 (D_MODEL*D_INNER/8)    // 262144
__global__ __launch_bounds__(256) void cvt_all(
    const float* __restrict__ u, const float* __restrict__ w_in,
    const float* __restrict__ w_out,
    u16* __restrict__ u_bf, u16* __restrict__ w_in_bf, u16* __restrict__ w_out_bf)
{
    int i = blockIdx.x * 256 + threadIdx.x;
    if (i < CVT_N0) {
        cp8(u, u_bf, i);
    } else if (i < CVT_N0 + CVT_N1) {
        int j = i - CVT_N0;
        int row = j >> 7, seg = j & 127;
        u16 o[8] = {0,0,0,0,0,0,0,0};
        if (row < D_IN_PROJ) {
            const float4* p = (const float4*)(w_in + (size_t)row * D_MODEL + seg * 8);
            float4 a = p[0], b = p[1];
            o[0]=f2bf(a.x); o[1]=f2bf(a.y); o[2]=f2bf(a.z); o[3]=f2bf(a.w);
            o[4]=f2bf(b.x); o[5]=f2bf(b.y); o[6]=f2bf(b.z); o[7]=f2bf(b.w);
        }
        *(uint4*)(w_in_bf + (size_t)j * 8) = *(const uint4*)o;
    } else if (i < CVT_N0 + CVT_N1 + CVT_N2) {
        cp8(w_out, w_out_bf, i - CVT_N0 - CVT_N1);
    }
}

// ---------------------------------------------------------------------------
// in_proj GEMM: 128x128 tile, BK=64, 8 waves (512 thr), counted vmcnt(4),
// T2 swizzle, rect per-XCD mapping, LDS-staged coalesced epilogue.
// ---------------------------------------------------------------------------
#define CPITCH 136    // u16 pitch for epilogue tile (272B rows, 16B aligned)
__global__ __launch_bounds__(512) void gemm_in512(
    const u16* __restrict__ A, const u16* __restrict__ B, int K,
    u16* __restrict__ C0, int n1, int ld0,
    u16* __restrict__ C1, int n2, int ld1,
    u16* __restrict__ C2, int n3, int ld2)
{
    __shared__ u16 smem[4 * 128 * 64];          // 64 KB arena

    const int tid  = threadIdx.x;
    const int wid  = tid >> 6;               // 0..7
    const int lane = tid & 63;
    const int wm   = wid >> 2, wn = wid & 3; // 2 x 4 wave grid

    // rectangular XCD mapping: grid 34x32 = 1088 = 8 XCD x (8m x 17n)
    const int gx   = gridDim.x;                  // 34
    int orig = blockIdx.y * gx + blockIdx.x;     // 0..1087
    const int xcd = orig & 7;
    const int loc = orig >> 3;                   // 0..135
    const int mt  = (xcd >> 1) * 8  + (loc & 7); // 0..31
    const int nt  = (xcd & 1) * 17 + (loc >> 3); // 0..33
    const int m0 = mt * 128, n0 = nt * 128;

    const int lrow = lane >> 3;
    const int lseg = (lane & 7) ^ lrow;
    const u16* gA = A + (size_t)(m0 + lrow) * K + lseg * 8;
    const u16* gB = B + (size_t)(n0 + lrow) * K + lseg * 8;

    f32x4 acc[4][2];
    #pragma unroll
    for (int i = 0; i < 4; ++i)
        #pragma unroll
        for (int j = 0; j < 2; ++j)
            acc[i][j] = (f32x4){0.f, 0.f, 0.f, 0.f};

    const int fr = lane & 15, fq = lane >> 4;
    const int nstep = K >> 6;

    auto stage = [&](int buf, int k0) {
        u16* sAp = smem + buf * 8192;
        u16* sBp = smem + 16384 + buf * 8192;
        #pragma unroll
        for (int i = 0; i < 2; ++i) {
            const int r0 = (i * 8 + wid) * 8;
            gload16(gA + (size_t)r0 * K + k0, sAp + r0 * 64);
            gload16(gB + (size_t)r0 * K + k0, sBp + r0 * 64);
        }
    };

    stage(0, 0);
    int cur = 0;
    for (int step = 0; step < nstep; ++step) {
        if (step + 1 < nstep) {
            stage(cur ^ 1, (step + 1) * 64);
            asm volatile("s_waitcnt vmcnt(4)" ::: "memory");
        } else {
            asm volatile("s_waitcnt vmcnt(0)" ::: "memory");
        }
        __builtin_amdgcn_s_barrier();
        __builtin_amdgcn_sched_barrier(0);

        const u16* sAc = smem + cur * 8192;
        const u16* sBc = smem + 16384 + cur * 8192;
        #pragma unroll
        for (int ks = 0; ks < 2; ++ks) {
            s16x8 bfr[2];
            #pragma unroll
            for (int ni = 0; ni < 2; ++ni) {
                const int row = wn * 32 + ni * 16 + fr;
                const int bo = row * 128 + ((ks * 64 + fq * 16) ^ ((row & 7) << 4));
                bfr[ni] = *(const s16x8*)((const char*)sBc + bo);
            }
            #pragma unroll
            for (int mi = 0; mi < 4; ++mi) {
                const int row = wm * 64 + mi * 16 + fr;
                const int bo = row * 128 + ((ks * 64 + fq * 16) ^ ((row & 7) << 4));
                s16x8 af = *(const s16x8*)((const char*)sAc + bo);
                #pragma unroll
                for (int ni = 0; ni < 2; ++ni)
                    acc[mi][ni] = __builtin_amdgcn_mfma_f32_16x16x32_bf16(
                        af, bfr[ni], acc[mi][ni], 0, 0, 0);
            }
        }

        __builtin_amdgcn_sched_barrier(0);
        __builtin_amdgcn_s_barrier();
        cur ^= 1;
    }
    __builtin_amdgcn_sched_barrier(0);   // keep epilogue ds_writes after loop

    // ---- LDS-staged epilogue: frag layout -> row-linear -> 16B stores ----
    u16* sC = smem;                       // K-loop buffers dead now
    #pragma unroll
    for (int mi = 0; mi < 4; ++mi) {
        #pragma unroll
        for (int j = 0; j < 4; ++j) {
            const int rl = wm * 64 + mi * 16 + fq * 4 + j;
            #pragma unroll
            for (int ni = 0; ni < 2; ++ni) {
                const int cl = wn * 32 + ni * 16 + fr;
                sC[rl * CPITCH + cl] = f2bf(acc[mi][ni][j]);
            }
        }
    }
    __syncthreads();
    #pragma unroll
    for (int k2 = 0; k2 < 4; ++k2) {
        const int g  = tid + k2 * 512;        // 0..2047
        const int rl = g >> 4, cg = g & 15;
        uint4 v = *(const uint4*)&sC[rl * CPITCH + cg * 8];
        const int r = m0 + rl, c = n0 + cg * 8;
        if (c < n1)      *(uint4*)(C0 + (size_t)r * ld0 + c)        = v;
        else if (c < n2) *(uint4*)(C1 + (size_t)r * ld1 + (c - n1)) = v;
        else if (c < n3) *(uint4*)(C2 + (size_t)r * ld2 + (c - n2)) = v;
    }
}

// ---------------------------------------------------------------------------
// out_proj GEMM: 128x128 tile, BK=64, 8 waves (512 thr), counted vmcnt(4),
// LDS-staged f32 epilogue in two 64-row halves (coalesced 16B stores).
// ---------------------------------------------------------------------------
__global__ __launch_bounds__(512) void gemm_out512(
    const u16* __restrict__ A, const u16* __restrict__ B, int K,
    float* __restrict__ C, int N)
{
    __shared__ u16 smem[4 * 128 * 64];          // 64 KB arena

    const int tid  = threadIdx.x;
    const int wid  = tid >> 6;               // 0..7
    const int lane = tid & 63;
    const int wm   = wid >> 2, wn = wid & 3; // 2 x 4 wave grid

    const int gx   = gridDim.x;
    const int nwg  = gx * gridDim.y;
    const int cpx  = nwg >> 3;
    int orig = blockIdx.y * gx + blockIdx.x;
    int wg   = (orig & 7) * cpx + (orig >> 3);
    const int m0 = (wg / gx) * 128, n0 = (wg % gx) * 128;

    const int lrow = lane >> 3;
    const int lseg = (lane & 7) ^ lrow;
    const u16* gA = A + (size_t)(m0 + lrow) * K + lseg * 8;
    const u16* gB = B + (size_t)(n0 + lrow) * K + lseg * 8;

    f32x4 acc[4][2];
    #pragma unroll
    for (int i = 0; i < 4; ++i)
        #pragma unroll
        for (int j = 0; j < 2; ++j)
            acc[i][j] = (f32x4){0.f, 0.f, 0.f, 0.f};

    const int fr = lane & 15, fq = lane >> 4;
    const int nstep = K >> 6;

    auto stage = [&](int buf, int k0) {
        u16* sAp = smem + buf * 8192;
        u16* sBp = smem + 16384 + buf * 8192;
        #pragma unroll
        for (int i = 0; i < 2; ++i) {
            const int r0 = (i * 8 + wid) * 8;
            gload16(gA + (size_t)r0 * K + k0, sAp + r0 * 64);
            gload16(gB + (size_t)r0 * K + k0, sBp + r0 * 64);
        }
    };

    stage(0, 0);
    int cur = 0;
    for (int step = 0; step < nstep; ++step) {
        if (step + 1 < nstep) {
            stage(cur ^ 1, (step + 1) * 64);
            asm volatile("s_waitcnt vmcnt(4)" ::: "memory");
        } else {
            asm volatile("s_waitcnt vmcnt(0)" ::: "memory");
        }
        __builtin_amdgcn_s_barrier();
        __builtin_amdgcn_sched_barrier(0);

        const u16* sAc = smem + cur * 8192;
        const u16* sBc = smem + 16384 + cur * 8192;
        #pragma unroll
        for (int ks = 0; ks < 2; ++ks) {
            s16x8 bfr[2];
            #pragma unroll
            for (int ni = 0; ni < 2; ++ni) {
                const int row = wn * 32 + ni * 16 + fr;
                const int bo = row * 128 + ((ks * 64 + fq * 16) ^ ((row & 7) << 4));
                bfr[ni] = *(const s16x8*)((const char*)sBc + bo);
            }
            #pragma unroll
            for (int mi = 0; mi < 4; ++mi) {
                const int row = wm * 64 + mi * 16 + fr;
                const int bo = row * 128 + ((ks * 64 + fq * 16) ^ ((row & 7) << 4));
                s16x8 af = *(const s16x8*)((const char*)sAc + bo);
                #pragma unroll
                for (int ni = 0; ni < 2; ++ni)
                    acc[mi][ni] = __builtin_amdgcn_mfma_f32_16x16x32_bf16(
                        af, bfr[ni], acc[mi][ni], 0, 0, 0);
            }
        }

        __builtin_amdgcn_sched_barrier(0);
        __builtin_amdgcn_s_barrier();
        cur ^= 1;
    }
    __builtin_amdgcn_sched_barrier(0);

    // ---- LDS-staged f32 epilogue, two 64-row halves (pitch 132 f32) ----
    float* sCf = (float*)smem;            // 64x132x4 = 33.8 KB per half
    #pragma unroll
    for (int h2 = 0; h2 < 2; ++h2) {
        if (wm == h2) {
            #pragma unroll
            for (int mi = 0; mi < 4; ++mi)
                #pragma unroll
                for (int j = 0; j < 4; ++j) {
                    const int rl = mi * 16 + fq * 4 + j;        // 0..63
                    #pragma unroll
                    for (int ni = 0; ni < 2; ++ni) {
                        const int cl = wn * 32 + ni * 16 + fr;
                        sCf[rl * 132 + cl] = acc[mi][ni][j];
                    }
                }
        }
        __syncthreads();
        #pragma unroll
        for (int k2 = 0; k2 < 4; ++k2) {
            const int g  = tid + k2 * 512;    // 0..2047
            const int rl = g >> 5, cg = g & 31;
            float4 v = *(const float4*)&sCf[rl * 132 + cg * 4];
            *(float4*)(C + (size_t)(m0 + h2 * 64 + rl) * N + n0 + cg * 4) = v;
        }
        __syncthreads();
    }
}

// ---------------------------------------------------------------------------
// Depthwise causal conv(4)+bias+SiLU (8 ch/thread) and, in tail blocks,
// dt = softplus(dtraw + dt_bias)  (merged to save a dispatch).
// ---------------------------------------------------------------------------
#define NCONV8 (NROWS*(CONV_DIM/8))
__global__ __launch_bounds__(256) void conv_silu_dt(
    const u16* __restrict__ xBC, const float* __restrict__ conv_w,
    const float* __restrict__ conv_b, u16* __restrict__ xconv,
    const u16* __restrict__ dtraw, const float* __restrict__ dt_bias,
    float* __restrict__ dtw)
{
    int idx = blockIdx.x * 256 + threadIdx.x;
    if (idx < NCONV8) {
        int c8  = idx % (CONV_DIM / 8);
        int row = idx / (CONV_DIM / 8);     // b*SEQLEN + l
        int l   = row % SEQLEN;
        int b   = row / SEQLEN;
        int c0  = c8 * 8;
        const u16* src = xBC + (size_t)(b * SEQLEN) * CONV_DIM + c0;

        uint4 z4 = {0u, 0u, 0u, 0u};
        uint4 v3 = *(const uint4*)(src + (size_t)l * CONV_DIM);
        uint4 v2 = (l >= 1) ? *(const uint4*)(src + (size_t)(l-1) * CONV_DIM) : z4;
        uint4 v1 = (l >= 2) ? *(const uint4*)(src + (size_t)(l-2) * CONV_DIM) : z4;
        uint4 v0 = (l >= 3) ? *(const uint4*)(src + (size_t)(l-3) * CONV_DIM) : z4;
        const u16* p0 = (const u16*)&v0; const u16* p1 = (const u16*)&v1;
        const u16* p2 = (const u16*)&v2; const u16* p3 = (const u16*)&v3;

        u16 o[8];
        #pragma unroll
        for (int j = 0; j < 8; ++j) {
            const float4 w4 = *(const float4*)(conv_w + (size_t)(c0 + j) * 4);
            float acc = conv_b[c0 + j]
                      + bf2f(p0[j]) * w4.x + bf2f(p1[j]) * w4.y
                      + bf2f(p2[j]) * w4.z + bf2f(p3[j]) * w4.w;
            o[j] = f2bf(acc / (1.f + expf(-acc)));   // SiLU
        }
        *(uint4*)(xconv + (size_t)row * CONV_DIM + c0) = *(const uint4*)o;
    } else {
        int k = idx - NCONV8;
        if (k < NROWS * NHEADS) {
            int h = k & (NHEADS - 1);
            float v = bf2f(dtraw[k]) + dt_bias[h];
            dtw[k] = (v > 20.f) ? v : log1pf(expf(v));
        }
    }
}

// ---------------------------------------------------------------------------
// Phase A v2: chunk state via MFMA.
// S[n][p] = sum_s WB[s][n] * x[s][p]  ->  dense 64x128 GEMM, K=s=64.
// sWBT[64 n][64 s] and sXT[128 p][64 s] built by swizzled transposed scatter
// (chunk_output-verified patterns); 16 MFMA/wave; LDS-staged epilogue.
// ---------------------------------------------------------------------------
__global__ __launch_bounds__(256) void chunk_state(
    const u16* __restrict__ xconv, const float* __restrict__ dtw,
    const float* __restrict__ A_log, u16* __restrict__ Sbuf,
    float* __restrict__ Tbuf)
{
    const int blk = blockIdx.x;
    const int k  = blk & (NCHUNK-1);
    const int bh = blk >> 5;
    const int b  = bh >> 4, h = bh & 15;
    const int tid = threadIdx.x;
    const int wid = tid >> 6, lane = tid & 63;
    const float A = -expf(A_log[h]);

    __shared__ u16 arena[12288];         // 24 KB: [sWBT 8KB | sXT 16KB]
    u16* sWBT = arena;                   // [64 n][64 s] bf16, 128B rows, swz
    u16* sXT  = arena + 4096;            // [128 p][64 s] bf16, 128B rows, swz
    u16* eT   = arena;                   // epilogue [64][CPITCH] (17.4 KB)
    float* sdt = (float*)arena;          // alias bytes 0..255
    float* sW  = sdt + CHUNK;            // alias bytes 256..511

    const int t0 = k * CHUNK;
    const u16* xc = xconv + (size_t)(b*SEQLEN + t0) * CONV_DIM;

    if (tid < CHUNK)
        sdt[tid] = dtw[(size_t)(b*SEQLEN + t0 + tid)*NHEADS + h];
    __syncthreads();
    if (tid < CHUNK) {
        float a = 0.f, pref = 0.f;
        for (int r = 0; r < CHUNK; ++r) {
            a += sdt[r] * A;
            if (r == tid) pref = a;
        }
        sW[tid] = __expf(a - pref) * sdt[tid];   // exp(T - L_s) * dt_s
        if (tid == 0) Tbuf[bh*NCHUNK + k] = a;   // a == T here
    }
    __syncthreads();

    // preload sW for this thread's staging row (before arena overwrite)
    const int s_stg = tid >> 2;          // staging source row 0..63
    const float wv = sW[s_stg];
    __syncthreads();                     // all sdt/sW reads done

    // ---- stage WBT: transposed swizzled scatter (rows n, col s) ----
    {
        const int nb = tid & 3;
        uint4 b0 = *(const uint4*)(xc + (size_t)s_stg*CONV_DIM + D_INNER + nb*16);
        uint4 b1 = *(const uint4*)(xc + (size_t)s_stg*CONV_DIM + D_INNER + nb*16 + 8);
        const u16* pb0 = (const u16*)&b0; const u16* pb1 = (const u16*)&b1;
        const int cb = s_stg * 2, cbase = (cb & ~15), coff = (cb & 15);
        #pragma unroll
        for (int j = 0; j < 16; ++j) {
            const int n = nb * 16 + j;
            const u16 val = f2bf(wv * bf2f(j < 8 ? pb0[j] : pb1[j - 8]));
            const int bo = n * 128 + (cbase ^ ((n & 7) << 4)) + coff;
            *(u16*)((char*)sWBT + bo) = val;
        }
    }
    // ---- stage XT: transposed swizzled scatter (rows p, col s) ----
    {
        const int pg = tid & 3;
        const int cb = s_stg * 2, cbase = (cb & ~15), coff = (cb & 15);
        #pragma unroll
        for (int i = 0; i < 4; ++i) {
            const int pb = pg * 32 + i * 8;
            uint4 xv = *(const uint4*)(xc + (size_t)s_stg*CONV_DIM + h*HEADDIM + pb);
            const u16* xp = (const u16*)&xv;
            #pragma unroll
            for (int j = 0; j < 8; ++j) {
                const int p = pb + j;
                const int bo = p * 128 + (cbase ^ ((p & 7) << 4)) + coff;
                *(u16*)((char*)sXT + bo) = xp[j];
            }
        }
    }
    __syncthreads();

    // ---- MFMA: S[n][p], A-frag = sWBT rows, B-frag = sXT rows ----
    const int fr = lane & 15, fq = lane >> 4;
    f32x4 accS[8];
    #pragma unroll
    for (int i = 0; i < 8; ++i) accS[i] = (f32x4){0.f, 0.f, 0.f, 0.f};

    #pragma unroll
    for (int ks = 0; ks < 2; ++ks) {
        const int nrow = wid * 16 + fr;
        const int boA = nrow * 128 + ((ks * 64 + fq * 16) ^ ((nrow & 7) << 4));
        s16x8 afr = *(const s16x8*)((const char*)sWBT + boA);
        #pragma unroll
        for (int pt = 0; pt < 8; ++pt) {
            const int p = pt * 16 + fr;
            const int boB = p * 128 + ((ks * 64 + fq * 16) ^ ((p & 7) << 4));
            s16x8 bfrB = *(const s16x8*)((const char*)sXT + boB);
            accS[pt] = __builtin_amdgcn_mfma_f32_16x16x32_bf16(afr, bfrB, accS[pt], 0, 0, 0);
        }
    }
    __syncthreads();     // all frag reads done before eT overwrite

    // ---- epilogue: frag -> eT row-linear -> coalesced 16B stores ----
    #pragma unroll
    for (int pt = 0; pt < 8; ++pt) {
        #pragma unroll
        for (int r = 0; r < 4; ++r) {
            const int n = wid * 16 + fq * 4 + r;
            eT[n * CPITCH + pt * 16 + fr] = f2bf(accS[pt][r]);
        }
    }
    __syncthreads();
    u16* So = Sbuf + ((size_t)bh*NCHUNK + k)*(D_STATE*HEADDIM);
    #pragma unroll
    for (int k2 = 0; k2 < 4; ++k2) {
        const int g  = tid + k2 * 256;        // 0..1023 = 64 rows x 16 groups
        const int rl = g >> 4, cg = g & 15;
        uint4 v = *(const uint4*)&eT[rl * CPITCH + cg * 8];
        *(uint4*)(So + (size_t)rl * HEADDIM + cg * 8) = v;
    }
}

// ---------------------------------------------------------------------------
// Inter-chunk sequential pass (bf16 S, f32 accumulation), parallel over (n,p)
// ---------------------------------------------------------------------------
__global__ __launch_bounds__(256) void chunk_seq_par(u16* __restrict__ Sbuf,
                                                     const float* __restrict__ Tbuf)
{
    const int blk = blockIdx.x;           // 32 bh * 8 = 256 blocks
    const int bh  = blk >> 3;
    const int sub = blk & 7;
    __shared__ float seT[NCHUNK];
    if (threadIdx.x < NCHUNK)
        seT[threadIdx.x] = __expf(Tbuf[bh*NCHUNK + threadIdx.x]);
    __syncthreads();

    const int idx4 = sub * 256 + threadIdx.x;    // 4-elem index in [0,2048)
    u16* base = Sbuf + (size_t)bh*NCHUNK*(D_STATE*HEADDIM) + (size_t)idx4*4;
    float run[4];
    #pragma unroll
    for (int j = 0; j < 4; ++j) run[j] = 0.f;
    for (int k = 0; k < NCHUNK; ++k) {
        u16* p = base + (size_t)k * (D_STATE*HEADDIM);
        uint2 v = *(const uint2*)p;
        const u16* pv = (const u16*)&v;
        const float eT = seT[k];
        u16 o[4];
        #pragma unroll
        for (int j = 0; j < 4; ++j) {
            float tmp = bf2f(pv[j]);
            o[j] = f2bf(run[j]);
            run[j] = run[j] * eT + tmp;
        }
        *(uint2*)p = *(const uint2*)o;
    }
}

// ---------------------------------------------------------------------------
// Phase B v2: stage B via MFMA.
// Mfull[64 t][128 k] (k = s' 0..63 = causal-masked M; 64..127 = Mext), swz.
// X and Sinit transposed in-kernel to sXT[p][s], sST[p][n] (swz) from global.
// Y = Mfull @ [X;Sinit]^T-operand form: 32 MFMA/wave.  48 KB LDS.
// ---------------------------------------------------------------------------
__global__ __launch_bounds__(256) void chunk_output(
    const u16* __restrict__ xconv, const float* __restrict__ dtw,
    const float* __restrict__ A_log, const float* __restrict__ D_param,
    const u16* __restrict__ Sbuf, u16* __restrict__ y)
{
    const int blk = blockIdx.x;
    const int k  = blk & (NCHUNK-1);
    const int bh = blk >> 5;
    const int b  = bh >> 4, h = bh & 15;
    const int tid = threadIdx.x;
    const int wid = tid >> 6, lane = tid & 63;
    const float A  = -expf(A_log[h]);
    const float Dp = D_param[h];

    __shared__ u16 arena[3 * 8192];      // 48 KB: [Mfull | sXT | sST]
    u16* Mfull = arena;                  // [64 t][128 k] bf16, 256B rows, swz
    u16* sXT   = arena + 8192;           // [128 p][64 s] bf16, 128B rows, swz
    u16* sST   = arena + 16384;          // [128 p][64 n] bf16, 128B rows, swz
    u16* eT    = arena + 8192;           // epilogue tile [64][CPITCH] (17 KB)
    float* sdt = (float*)Mfull;          // alias rows t=0,1 (512 B)
    float* sL  = sdt + CHUNK;

    const int t0 = k * CHUNK;
    const u16* xc = xconv + (size_t)(b*SEQLEN + t0) * CONV_DIM;
    const u16* Sinit = Sbuf + ((size_t)bh*NCHUNK + k)*(D_STATE*HEADDIM);

    if (tid < CHUNK)
        sdt[tid] = dtw[(size_t)(b*SEQLEN + t0 + tid)*NHEADS + h];
    __syncthreads();
    if (tid < CHUNK) {
        float a = 0.f, pref = 0.f;
        for (int r = 0; r < CHUNK; ++r) {
            a += sdt[r] * A;
            if (r == tid) pref = a;
        }
        sL[tid] = pref;
    }
    __syncthreads();

    // ---- PRELOAD from sdt/sL into registers (before Mfull overwrite) ----
    const int fr = lane & 15, fq = lane >> 4;
    float4 sL4 = *(const float4*)&sL[wid * 16 + fq * 4];
    const float Lt[4] = {sL4.x, sL4.y, sL4.z, sL4.w};
    float pre_L[4], pre_dt[4];
    #pragma unroll
    for (int sf = 0; sf < 4; ++sf) {
        const int s_row = sf * 16 + fr;
        pre_L[sf]  = sL[s_row];
        pre_dt[sf] = sdt[s_row];
    }
    const int tM = tid >> 2, nbM = tid & 3;           // Mext coords
    const float elM = __expf(sL[tM]);
    __syncthreads();     // all alias reads done before Mfull writes

    // ---- P2: transpose X and Sinit into sXT / sST (swizzled scatter) ----
    {
        const int sr = tid >> 2;          // source row 0..63
        const int pg = tid & 3;           // p-group 0..3
        #pragma unroll
        for (int i = 0; i < 4; ++i) {
            const int pb = pg * 32 + i * 8;
            uint4 xv = *(const uint4*)(xc + (size_t)sr * CONV_DIM + h * HEADDIM + pb);
            const u16* xp = (const u16*)&xv;
            uint4 sv = *(const uint4*)(Sinit + (size_t)sr * HEADDIM + pb);
            const u16* sp = (const u16*)&sv;
            const int cb = sr * 2;                       // col byte in dest row
            const int cbase = (cb & ~15), coff = (cb & 15);
            #pragma unroll
            for (int j = 0; j < 8; ++j) {
                const int p = pb + j;
                const int bo = p * 128 + (cbase ^ ((p & 7) << 4)) + coff;
                *(u16*)((char*)sXT + bo) = xp[j];
                *(u16*)((char*)sST + bo) = sp[j];
            }
        }
    }

    // ---- P3: stage A MFMA (G = C@B^T from global) -> Mfull[t][s] ----
    {
        const int t_row = wid * 16 + fr;
        s16x8 cfrag[2];
        #pragma unroll
        for (int ks = 0; ks < 2; ++ks)
            cfrag[ks] = *(const s16x8*)(xc + (size_t)t_row*CONV_DIM + D_INNER + D_STATE
                                        + ks*32 + fq*8);

        #pragma unroll
        for (int sf = 0; sf < 4; ++sf) {
            const int s_row = sf * 16 + fr;
            f32x4 g = (f32x4){0.f, 0.f, 0.f, 0.f};
            #pragma unroll
            for (int ks = 0; ks < 2; ++ks) {
                s16x8 bfrag = *(const s16x8*)(xc + (size_t)s_row*CONV_DIM + D_INNER
                                              + ks*32 + fq*8);
                g = __builtin_amdgcn_mfma_f32_16x16x32_bf16(cfrag[ks], bfrag, g, 0, 0, 0);
            }
            const float Ls  = pre_L[sf];
            const float dts = pre_dt[sf];
            const int cb = s_row * 2;
            const int cbase = (cb & ~15), coff = (cb & 15);
            #pragma unroll
            for (int r = 0; r < 4; ++r) {
                const int t = wid * 16 + fq * 4 + r;
                const float e = __expf(fminf(Lt[r] - Ls, 0.f)) * dts;
                const float val = (s_row <= t) ? g[r] * e : 0.f;
                const int bo = t * 256 + (cbase ^ ((t & 7) << 4)) + coff;
                *(u16*)((char*)Mfull + bo) = f2bf(val);
            }
        }
    }
    // ---- Mext rows: Mfull[t][64+n] = exp(L_t) * C_t[n] (uint4 writes) ----
    {
        uint4 c0 = *(const uint4*)(xc + (size_t)tM*CONV_DIM + D_INNER + D_STATE + nbM*16);
        uint4 c1 = *(const uint4*)(xc + (size_t)tM*CONV_DIM + D_INNER + D_STATE + nbM*16 + 8);
        const u16* pc0 = (const u16*)&c0; const u16* pc1 = (const u16*)&c1;
        u16 o[16];
        #pragma unroll
        for (int j = 0; j < 16; ++j)
            o[j] = f2bf(elM * bf2f(j < 8 ? pc0[j] : pc1[j - 8]));
        #pragma unroll
        for (int u2 = 0; u2 < 2; ++u2) {
            const int cb = 128 + nbM * 32 + u2 * 16;     // col byte (k=64+n)
            const int bo = tM * 256 + (cb ^ ((tM & 7) << 4));
            *(uint4*)((char*)Mfull + bo) = *(const uint4*)&o[u2 * 8];
        }
    }
    __syncthreads();

    // ---- P4: stage B MFMA: Y[t][p] = Mfull[t][k] @ XS^T[p][k] ----
    f32x4 accB[8];
    #pragma unroll
    for (int i = 0; i < 8; ++i) accB[i] = (f32x4){0.f, 0.f, 0.f, 0.f};

    #pragma unroll
    for (int ks = 0; ks < 4; ++ks) {
        const int ta = wid * 16 + fr;
        const int boA = ta * 256 + ((ks * 64 + fq * 16) ^ ((ta & 7) << 4));
        s16x8 afr = *(const s16x8*)((const char*)Mfull + boA);
        const u16* src = (ks < 2) ? sXT : sST;
        const int cbB = (ks & 1) * 64 + fq * 16;
        #pragma unroll
        for (int pt = 0; pt < 8; ++pt) {
            const int p = pt * 16 + fr;
            const int boB = p * 128 + (cbB ^ ((p & 7) << 4));
            s16x8 bfrB = *(const s16x8*)((const char*)src + boB);
            accB[pt] = __builtin_amdgcn_mfma_f32_16x16x32_bf16(afr, bfrB, accB[pt], 0, 0, 0);
        }
    }

    // ---- D*x in fragment layout (reads sXT scalar) ----
    #pragma unroll
    for (int pt = 0; pt < 8; ++pt) {
        const int p = pt * 16 + fr;
        #pragma unroll
        for (int r = 0; r < 4; ++r) {
            const int t = wid * 16 + fq * 4 + r;
            const int cb = t * 2;
            const int bo = p * 128 + ((cb & ~15) ^ ((p & 7) << 4)) + (cb & 15);
            accB[pt][r] += Dp * bf2f(*(const u16*)((const char*)sXT + bo));
        }
    }
    __syncthreads();     // all sXT/sST reads done before eT overwrite

    // ---- epilogue: frag -> eT row-linear -> coalesced stores ----
    #pragma unroll
    for (int pt = 0; pt < 8; ++pt) {
        #pragma unroll
        for (int r = 0; r < 4; ++r) {
            const int t = wid * 16 + fq * 4 + r;
            eT[t * CPITCH + pt * 16 + fr] = f2bf(accB[pt][r]);
        }
    }
    __syncthreads();
    #pragma unroll
    for (int k2 = 0; k2 < 4; ++k2) {
        const int g  = tid + k2 * 256;        // 0..1023 = 64 rows x 16 groups
        const int rl = g >> 4, cg = g & 15;
        uint4 v = *(const uint4*)&eT[rl * CPITCH + cg * 8];
        *(uint4*)(y + ((size_t)(b*SEQLEN + t0 + rl))*D_INNER + h*HEADDIM + cg*8) = v;
    }
}

// ---------------------------------------------------------------------------
// yg = y * silu(z); RMSNorm over D_INNER; bf16 in, bf16 out
// ---------------------------------------------------------------------------
__global__ __launch_bounds__(256) void gate_rmsnorm(const u16* __restrict__ z,
                                                    const u16* __restrict__ y,
                                                    const float* __restrict__ norm_w,
                                                    u16* __restrict__ yn)
{
    const int row = blockIdx.x;
    const int tid = threadIdx.x;
    const u16* zr = z + (size_t)row * D_INNER + tid * 8;
    const u16* yr = y + (size_t)row * D_INNER + tid * 8;
    u16*       o  = yn + (size_t)row * D_INNER + tid * 8;

    uint4 zv4 = *(const uint4*)zr;
    uint4 yv4 = *(const uint4*)yr;
    const u16* zp = (const u16*)&zv4;
    const u16* yp = (const u16*)&yv4;

    float vals[8];
    float ss = 0.f;
    #pragma unroll
    for (int j = 0; j < 8; ++j) {
        float zv = bf2f(zp[j]);
        float g  = bf2f(yp[j]) * (zv / (1.f + expf(-zv)));
        vals[j] = g;
        ss += g * g;
    }
    #pragma unroll
    for (int off = 32; off > 0; off >>= 1) ss += __shfl_down(ss, off);
    __shared__ float red[4];
    __shared__ float sscale;
    int wid = tid >> 6, lane = tid & 63;
    if (lane == 0) red[wid] = ss;
    __syncthreads();
    if (tid == 0)
        sscale = rsqrtf((red[0]+red[1]+red[2]+red[3]) / (float)D_INNER + 1e-5f);
    __syncthreads();
    float rms = sscale;
    const float4* nw = (const float4*)(norm_w + tid * 8);
    float4 w0 = nw[0], w1 = nw[1];
    float wv[8] = {w0.x,w0.y,w0.z,w0.w,w1.x,w1.y,w1.z,w1.w};
    u16 ov[8];
    #pragma unroll
    for (int j = 0; j < 8; ++j) ov[j] = f2bf(vals[j] * rms * wv[j]);
    *(uint4*)o = *(const uint4*)ov;
}

// ---------------------------------------------------------------------------
extern "C" void kernel_launch(void* const* d_in, const int* in_sizes, int n_in,
                              void* d_out, int out_size, void* d_ws, size_t ws_size,
                              hipStream_t stream)
{
    const float* u          = (const float*)d_in[0];
    const float* in_proj_w  = (const float*)d_in[1];
    const float* conv_w     = (const float*)d_in[2];
    const float* conv_b     = (const float*)d_in[3];
    const float* dt_bias    = (const float*)d_in[4];
    const float* A_log      = (const float*)d_in[5];
    const float* D_param    = (const float*)d_in[6];
    const float* norm_w     = (const float*)d_in[7];
    const float* out_proj_w = (const float*)d_in[8];
    float* out = (float*)d_out;

    char* w = (char*)d_ws;
    u16* z_bf     = (u16*)w;  w += (size_t)NROWS * D_INNER  * 2;   // 16.78 MB
    u16* xBC_bf   = (u16*)w;  w += (size_t)NROWS * CONV_DIM * 2;   // 17.83 MB
    u16* xconv_bf = (u16*)w;  w += (size_t)NROWS * CONV_DIM * 2;   // 17.83 MB
    u16* yb_bf    = (u16*)w;  w += (size_t)NROWS * D_INNER  * 2;   // 16.78 MB
    u16* dtraw_bf = (u16*)w;  w += (size_t)NROWS * NHEADS   * 2;   // 0.13 MB
    float* dtw    = (float*)w; w += (size_t)NROWS * NHEADS  * 4;   // 0.26 MB
    float* Tbuf   = (float*)w; w += (size_t)BATCH*NHEADS*NCHUNK * 4;
    u16* Sbuf     = (u16*)w;  w += (size_t)BATCH*NHEADS*NCHUNK*D_STATE*HEADDIM * 2; // 16.78 MB
    u16* u_bf     = (u16*)w;  w += (size_t)NROWS * D_MODEL  * 2;   // 8.39 MB
    u16* w_in_bf  = (u16*)w;  w += (size_t)NPAD  * D_MODEL  * 2;   // 8.91 MB
    u16* w_out_bf = (u16*)w;  w += (size_t)D_MODEL * D_INNER * 2;  // 4.19 MB
    u16* yn_bf    = xconv_bf;   // xconv dead after chunk_output

    // 0) all f32 -> bf16 conversions in one dispatch
    cvt_all<<<(CVT_N0+CVT_N1+CVT_N2 + 255)/256, 256, 0, stream>>>(
        u, in_proj_w, out_proj_w, u_bf, w_in_bf, w_out_bf);

    // 1) in_proj GEMM (8-wave 512-thr); grid 34 x 32 = 1088 (rect mapping)
    dim3 g1(NPAD/128, NROWS/128);
    gemm_in512<<<g1, 512, 0, stream>>>(u_bf, w_in_bf, D_MODEL,
                                       z_bf, D_INNER, D_INNER,
                                       xBC_bf, D_INNER + CONV_DIM, CONV_DIM,
                                       dtraw_bf, D_IN_PROJ, NHEADS);

    // 2) conv + SiLU + dt softplus (merged)
    int ntot = NCONV8 + NROWS * NHEADS;
    conv_silu_dt<<<(ntot + 255) / 256, 256, 0, stream>>>(
        xBC_bf, conv_w, conv_b, xconv_bf, dtraw_bf, dt_bias, dtw);

    // 3) chunked scan (MFMA chunk_state + MFMA chunk_output)
    chunk_state<<<BATCH*NHEADS*NCHUNK, 256, 0, stream>>>(xconv_bf, dtw, A_log, Sbuf, Tbuf);
    chunk_seq_par<<<BATCH*NHEADS*8, 256, 0, stream>>>(Sbuf, Tbuf);
    chunk_output<<<BATCH*NHEADS*NCHUNK, 256, 0, stream>>>(xconv_bf, dtw, A_log, D_param,
                                                          Sbuf, yb_bf);

    // 4) gate + RMSNorm -> bf16
    gate_rmsnorm<<<NROWS, 256, 0, stream>>>(z_bf, yb_bf, norm_w, yn_bf);

    // 5) out_proj GEMM (8-wave 512-thr, LDS-staged f32 epilogue)
    dim3 g6(D_MODEL/128, NROWS/128);
    gemm_out512<<<g6, 512, 0, stream>>>(yn_bf, w_out_bf, D_INNER, out, D_MODEL);
}